// Round 1
// baseline (642.101 us; speedup 1.0000x reference)
//
#include <hip/hip_runtime.h>
#include <cstdint>

constexpr int B_  = 8;
constexpr int C_  = 128;
constexpr int CQ  = 16;
constexpr int T_  = 8;
constexpr int HW_ = 1024;
constexpr int P_  = T_ * HW_;   // 8192 positions per (b,c)
constexpr int F_  = CQ * T_;    // 128  PAM feature dim
constexpr int CT_ = C_ * T_;    // 1024

// ---------------------------------------------------------------------------
// QKV: 1x1x1 conv == per-position channel matmul. out[oc][p] = W[oc][:]·x[:][p]+b
// Block: 64 positions, all 160 output channels. x tile staged in LDS.
// ---------------------------------------------------------------------------
__global__ __launch_bounds__(256)
void k_qkv(const float* __restrict__ x,
           const float* __restrict__ Wq, const float* __restrict__ bq,
           const float* __restrict__ Wk, const float* __restrict__ bk,
           const float* __restrict__ Wv, const float* __restrict__ bv,
           float* __restrict__ q, float* __restrict__ k, float* __restrict__ v)
{
    __shared__ float xs[128][64];
    const int b   = blockIdx.y;
    const int p0  = blockIdx.x * 64;
    const int tid = threadIdx.x;

    #pragma unroll
    for (int r = 0; r < 8; r++) {
        int idx = r * 256 + tid;              // 0..2047
        int c   = idx >> 4;
        int pj  = (idx & 15) << 2;
        *(float4*)&xs[c][pj] =
            *(const float4*)&x[((size_t)(b * C_ + c)) * P_ + p0 + pj];
    }
    __syncthreads();

    const int pq = (tid & 15) << 2;           // 4 positions
    const int g  = tid >> 4;                  // 0..15 -> channels g*10..g*10+9

    const float* wrow[10];
    float*       orow[10];
    float4       acc[10];
    #pragma unroll
    for (int j = 0; j < 10; j++) {
        int oc = g * 10 + j;
        float bias;
        if (oc < 16)      { wrow[j] = Wq + oc * C_;        bias = bq[oc];
                            orow[j] = q + ((size_t)(b * CQ + oc)) * P_; }
        else if (oc < 32) { wrow[j] = Wk + (oc - 16) * C_; bias = bk[oc - 16];
                            orow[j] = k + ((size_t)(b * CQ + oc - 16)) * P_; }
        else              { wrow[j] = Wv + (oc - 32) * C_; bias = bv[oc - 32];
                            orow[j] = v + ((size_t)(b * C_ + oc - 32)) * P_; }
        acc[j] = make_float4(bias, bias, bias, bias);
    }

    for (int c4 = 0; c4 < 32; c4++) {
        float4 xv0 = *(float4*)&xs[c4 * 4 + 0][pq];
        float4 xv1 = *(float4*)&xs[c4 * 4 + 1][pq];
        float4 xv2 = *(float4*)&xs[c4 * 4 + 2][pq];
        float4 xv3 = *(float4*)&xs[c4 * 4 + 3][pq];
        #pragma unroll
        for (int j = 0; j < 10; j++) {
            float4 w = *(const float4*)&wrow[j][c4 * 4];
            acc[j].x += w.x * xv0.x + w.y * xv1.x + w.z * xv2.x + w.w * xv3.x;
            acc[j].y += w.x * xv0.y + w.y * xv1.y + w.z * xv2.y + w.w * xv3.y;
            acc[j].z += w.x * xv0.z + w.y * xv1.z + w.z * xv2.z + w.w * xv3.z;
            acc[j].w += w.x * xv0.w + w.y * xv1.w + w.z * xv2.w + w.w * xv3.w;
        }
    }
    #pragma unroll
    for (int j = 0; j < 10; j++)
        *(float4*)&orow[j][p0 + pq] = acc[j];
}

// ---------------------------------------------------------------------------
// Energy: E[b][n][m] = sum_f qf[b][f][n] * kf[b][f][m].  64x64 tile, K=128.
// ---------------------------------------------------------------------------
__global__ __launch_bounds__(256)
void k_energy(const float* __restrict__ q, const float* __restrict__ k,
              float* __restrict__ E)
{
    __shared__ float qs[128][64];
    __shared__ float ks[128][64];
    const int b  = blockIdx.z;
    const int n0 = blockIdx.y * 64, m0 = blockIdx.x * 64;
    const int tid = threadIdx.x;
    const float* qb = q + (size_t)b * F_ * HW_;
    const float* kb = k + (size_t)b * F_ * HW_;

    #pragma unroll
    for (int r = 0; r < 8; r++) {
        int idx = r * 256 + tid;
        int f = idx >> 4, nj = (idx & 15) << 2;
        *(float4*)&qs[f][nj] = *(const float4*)&qb[f * HW_ + n0 + nj];
        *(float4*)&ks[f][nj] = *(const float4*)&kb[f * HW_ + m0 + nj];
    }
    __syncthreads();

    const int tn = (tid & 15) << 2, tm = (tid >> 4) << 2;
    float acc[4][4] = {};
    for (int f = 0; f < 128; f++) {
        float4 a = *(float4*)&qs[f][tn];
        float4 c = *(float4*)&ks[f][tm];
        float av[4] = {a.x, a.y, a.z, a.w};
        float bv[4] = {c.x, c.y, c.z, c.w};
        #pragma unroll
        for (int i = 0; i < 4; i++)
            #pragma unroll
            for (int j = 0; j < 4; j++)
                acc[i][j] += av[i] * bv[j];
    }
    float* Eb = E + (size_t)b * HW_ * HW_;
    #pragma unroll
    for (int i = 0; i < 4; i++)
        *(float4*)&Eb[(size_t)(n0 + tn + i) * HW_ + m0 + tm] =
            make_float4(acc[i][0], acc[i][1], acc[i][2], acc[i][3]);
}

// ---------------------------------------------------------------------------
// Row softmax over last axis, in place. One block per row of 1024.
// ---------------------------------------------------------------------------
__global__ __launch_bounds__(256)
void k_softmax(float* __restrict__ E)
{
    float* e = E + (size_t)blockIdx.x * HW_;
    const int tid = threadIdx.x;
    float4 v = ((float4*)e)[tid];
    float m = fmaxf(fmaxf(v.x, v.y), fmaxf(v.z, v.w));
    #pragma unroll
    for (int off = 32; off; off >>= 1) m = fmaxf(m, __shfl_xor(m, off));
    __shared__ float s1[4], s2[4];
    if ((tid & 63) == 0) s1[tid >> 6] = m;
    __syncthreads();
    m = fmaxf(fmaxf(s1[0], s1[1]), fmaxf(s1[2], s1[3]));
    v.x = __expf(v.x - m); v.y = __expf(v.y - m);
    v.z = __expf(v.z - m); v.w = __expf(v.w - m);
    float s = v.x + v.y + v.z + v.w;
    #pragma unroll
    for (int off = 32; off; off >>= 1) s += __shfl_xor(s, off);
    if ((tid & 63) == 0) s2[tid >> 6] = s;
    __syncthreads();
    s = s2[0] + s2[1] + s2[2] + s2[3];
    float inv = 1.0f / s;
    v.x *= inv; v.y *= inv; v.z *= inv; v.w *= inv;
    ((float4*)e)[tid] = v;
}

// ---------------------------------------------------------------------------
// PV: out[b][ct][n] = gamma_pam * sum_m V[b][ct][m] * attn[b][n][m]
// 128x128 tile, K-chunks of 32, operands staged transposed (pitch 132).
// Writes directly into d_out.
// ---------------------------------------------------------------------------
__global__ __launch_bounds__(256)
void k_pv(const float* __restrict__ v, const float* __restrict__ A,
          const float* __restrict__ gamma_pam, float* __restrict__ out)
{
    __shared__ float Vs[32][132];
    __shared__ float As[32][132];
    const int b   = blockIdx.z;
    const int ct0 = blockIdx.y * 128, n0 = blockIdx.x * 128;
    const int tid = threadIdx.x;
    const float* vb = v + (size_t)b * CT_ * HW_;
    const float* ab = A + (size_t)b * HW_ * HW_;
    const int tc = (tid & 15) << 3, tn = (tid >> 4) << 3;
    float acc[8][8] = {};

    for (int mc = 0; mc < 1024; mc += 32) {
        #pragma unroll
        for (int r = 0; r < 4; r++) {
            int idx = r * 256 + tid;              // 0..1023
            int rr = idx >> 3, mj = (idx & 7) << 2;
            float4 vv = *(const float4*)&vb[(size_t)(ct0 + rr) * HW_ + mc + mj];
            float4 aa = *(const float4*)&ab[(size_t)(n0 + rr) * HW_ + mc + mj];
            Vs[mj + 0][rr] = vv.x; Vs[mj + 1][rr] = vv.y;
            Vs[mj + 2][rr] = vv.z; Vs[mj + 3][rr] = vv.w;
            As[mj + 0][rr] = aa.x; As[mj + 1][rr] = aa.y;
            As[mj + 2][rr] = aa.z; As[mj + 3][rr] = aa.w;
        }
        __syncthreads();
        for (int m = 0; m < 32; m++) {
            float4 a0 = *(float4*)&Vs[m][tc], a1 = *(float4*)&Vs[m][tc + 4];
            float4 b0 = *(float4*)&As[m][tn], b1 = *(float4*)&As[m][tn + 4];
            float av[8] = {a0.x, a0.y, a0.z, a0.w, a1.x, a1.y, a1.z, a1.w};
            float bv[8] = {b0.x, b0.y, b0.z, b0.w, b1.x, b1.y, b1.z, b1.w};
            #pragma unroll
            for (int i = 0; i < 8; i++)
                #pragma unroll
                for (int j = 0; j < 8; j++)
                    acc[i][j] += av[i] * bv[j];
        }
        __syncthreads();
    }

    const float gp = gamma_pam[0];
    float* ob = out + (size_t)b * CT_ * HW_;
    #pragma unroll
    for (int i = 0; i < 8; i++) {
        float4 w0 = make_float4(gp * acc[i][0], gp * acc[i][1],
                                gp * acc[i][2], gp * acc[i][3]);
        float4 w1 = make_float4(gp * acc[i][4], gp * acc[i][5],
                                gp * acc[i][6], gp * acc[i][7]);
        *(float4*)&ob[(size_t)(ct0 + tc + i) * HW_ + n0 + tn]     = w0;
        *(float4*)&ob[(size_t)(ct0 + tc + i) * HW_ + n0 + tn + 4] = w1;
    }
}

// ---------------------------------------------------------------------------
// CAM gram partials: part[b][ch][c][d] = sum over 256 n of x[c][n]x[d][n]
// ---------------------------------------------------------------------------
__global__ __launch_bounds__(256)
void k_cam_partial(const float* __restrict__ x, float* __restrict__ part)
{
    __shared__ float xs[64][132];
    const int b = blockIdx.y, ch = blockIdx.x;
    const int tid = threadIdx.x;
    const int n0 = ch * 256;
    const float* xb = x + (size_t)b * C_ * P_;
    const int tc = (tid & 15) << 3, td = (tid >> 4) << 3;
    float acc[8][8] = {};

    for (int sp = 0; sp < 4; sp++) {
        #pragma unroll
        for (int r = 0; r < 8; r++) {
            int idx = r * 256 + tid;            // 0..2047
            int c = idx >> 4, nj = (idx & 15) << 2;
            float4 xv = *(const float4*)&xb[(size_t)c * P_ + n0 + sp * 64 + nj];
            xs[nj + 0][c] = xv.x; xs[nj + 1][c] = xv.y;
            xs[nj + 2][c] = xv.z; xs[nj + 3][c] = xv.w;
        }
        __syncthreads();
        for (int n = 0; n < 64; n++) {
            float4 a0 = *(float4*)&xs[n][tc], a1 = *(float4*)&xs[n][tc + 4];
            float4 b0 = *(float4*)&xs[n][td], b1 = *(float4*)&xs[n][td + 4];
            float av[8] = {a0.x, a0.y, a0.z, a0.w, a1.x, a1.y, a1.z, a1.w};
            float bv[8] = {b0.x, b0.y, b0.z, b0.w, b1.x, b1.y, b1.z, b1.w};
            #pragma unroll
            for (int i = 0; i < 8; i++)
                #pragma unroll
                for (int j = 0; j < 8; j++)
                    acc[i][j] += av[i] * bv[j];
        }
        __syncthreads();
    }
    float* pb = part + ((size_t)(b * 32 + ch)) * C_ * C_;
    #pragma unroll
    for (int i = 0; i < 8; i++) {
        *(float4*)&pb[(size_t)(tc + i) * C_ + td] =
            make_float4(acc[i][0], acc[i][1], acc[i][2], acc[i][3]);
        *(float4*)&pb[(size_t)(tc + i) * C_ + td + 4] =
            make_float4(acc[i][4], acc[i][5], acc[i][6], acc[i][7]);
    }
}

// ---------------------------------------------------------------------------
// CAM reduce + negated-energy softmax: a[c][d] = softmax_d(min_row - e)
// ---------------------------------------------------------------------------
__global__ __launch_bounds__(128)
void k_cam_reduce(const float* __restrict__ part, float* __restrict__ a_cam)
{
    const int b = blockIdx.y, c = blockIdx.x;
    const int d = threadIdx.x;                  // 0..127
    float s = 0.f;
    for (int ch = 0; ch < 32; ch++)
        s += part[(((size_t)(b * 32 + ch)) * C_ + c) * C_ + d];
    float mn = s;
    #pragma unroll
    for (int off = 32; off; off >>= 1) mn = fminf(mn, __shfl_xor(mn, off));
    __shared__ float m1[2], m2[2];
    if ((d & 63) == 0) m1[d >> 6] = mn;
    __syncthreads();
    mn = fminf(m1[0], m1[1]);
    float p = __expf(mn - s);
    float sum = p;
    #pragma unroll
    for (int off = 32; off; off >>= 1) sum += __shfl_xor(sum, off);
    if ((d & 63) == 0) m2[d >> 6] = sum;
    __syncthreads();
    sum = m2[0] + m2[1];
    a_cam[((size_t)(b * C_ + c)) * C_ + d] = p / sum;
}

// ---------------------------------------------------------------------------
// TIM gram: e_t[b][t][s] += sum over (c,hw) of x[b,c,t,hw] x[b,c,s,hw]
// ---------------------------------------------------------------------------
__global__ __launch_bounds__(256)
void k_tim_gram(const float* __restrict__ x, float* __restrict__ e_t)
{
    const int b = blockIdx.y, c = blockIdx.x;
    const int tid = threadIdx.x;
    const float* xb = x + ((size_t)(b * C_ + c)) * P_;
    float acc[8][8] = {};
    for (int r = 0; r < 4; r++) {
        int hw = r * 256 + tid;
        float xv[8];
        #pragma unroll
        for (int t = 0; t < 8; t++) xv[t] = xb[t * HW_ + hw];
        #pragma unroll
        for (int t = 0; t < 8; t++)
            #pragma unroll
            for (int s2 = 0; s2 < 8; s2++)
                acc[t][s2] += xv[t] * xv[s2];
    }
    __shared__ float sm[4][64];
    const int lane = tid & 63, wid = tid >> 6;
    #pragma unroll
    for (int u = 0; u < 64; u++) {
        float vv = acc[u >> 3][u & 7];
        #pragma unroll
        for (int off = 32; off; off >>= 1) vv += __shfl_xor(vv, off);
        if (lane == 0) sm[wid][u] = vv;
    }
    __syncthreads();
    if (tid < 64) {
        float vv = sm[0][tid] + sm[1][tid] + sm[2][tid] + sm[3][tid];
        atomicAdd(&e_t[b * 64 + tid], vv);
    }
}

// ---------------------------------------------------------------------------
// TIM softmax: 64 rows of 8 (B*T rows), negated-energy softmax
// ---------------------------------------------------------------------------
__global__ __launch_bounds__(512)
void k_tim_softmax(const float* __restrict__ e_t, float* __restrict__ a_t)
{
    const int tid = threadIdx.x;                // 0..511: b*64 + t*8 + s
    float v = e_t[tid];
    float mn = v;
    #pragma unroll
    for (int off = 4; off; off >>= 1) mn = fminf(mn, __shfl_xor(mn, off, 8));
    float p = __expf(mn - v);
    float s = p;
    #pragma unroll
    for (int off = 4; off; off >>= 1) s += __shfl_xor(s, off, 8);
    a_t[tid] = p / s;
}

// ---------------------------------------------------------------------------
// Final fused: out += gamma_cam * (a_cam @ x) + gamma_tim * (a_t @_t x) + 3x
// Block: batch b, 16 hw columns, all 128 c x 8 t.  x tile in LDS (64KB).
// ---------------------------------------------------------------------------
__global__ __launch_bounds__(256)
void k_final(const float* __restrict__ x, const float* __restrict__ a_cam,
             const float* __restrict__ a_t,
             const float* __restrict__ gamma_cam, const float* __restrict__ gamma_tim,
             float* __restrict__ out)
{
    __shared__ float xs[128][128];
    const int b   = blockIdx.y;
    const int hw0 = blockIdx.x * 16;
    const int tid = threadIdx.x;
    const float* xb = x + (size_t)b * C_ * P_;

    #pragma unroll
    for (int r = 0; r < 16; r++) {
        int idx = r * 256 + tid;                // 0..4095
        int c = idx >> 5, t = (idx >> 2) & 7, j4 = (idx & 3) << 2;
        *(float4*)&xs[c][t * 16 + j4] =
            *(const float4*)&xb[(size_t)c * P_ + t * HW_ + hw0 + j4];
    }
    __syncthreads();

    const int pos = tid & 127, chh = tid >> 7;  // c range = chh*64..+63
    const int t = pos >> 4, hwi = pos & 15;
    const float* ab = a_cam + (size_t)b * C_ * C_;

    float at[8];
    #pragma unroll
    for (int s2 = 0; s2 < 8; s2++) at[s2] = a_t[b * 64 + t * 8 + s2];

    float accc[64];
    #pragma unroll
    for (int j = 0; j < 64; j++) accc[j] = 0.f;

    for (int d4 = 0; d4 < 128; d4 += 4) {
        float xv0 = xs[d4 + 0][pos], xv1 = xs[d4 + 1][pos];
        float xv2 = xs[d4 + 2][pos], xv3 = xs[d4 + 3][pos];
        #pragma unroll
        for (int j = 0; j < 64; j++) {
            float4 a4 = *(const float4*)&ab[(size_t)(chh * 64 + j) * C_ + d4];
            accc[j] += a4.x * xv0 + a4.y * xv1 + a4.z * xv2 + a4.w * xv3;
        }
    }

    const float gc = gamma_cam[0], gt = gamma_tim[0];
    float* ob = out + (size_t)b * C_ * P_;
    #pragma unroll
    for (int j = 0; j < 64; j++) {
        int c = chh * 64 + j;
        float tim = 0.f;
        #pragma unroll
        for (int s2 = 0; s2 < 8; s2++) tim += at[s2] * xs[c][s2 * 16 + hwi];
        size_t oi = (size_t)c * P_ + t * HW_ + hw0 + hwi;
        ob[oi] += gc * accc[j] + gt * tim + 3.0f * xs[c][pos];
    }
}

// ---------------------------------------------------------------------------
extern "C" void kernel_launch(void* const* d_in, const int* in_sizes, int n_in,
                              void* d_out, int out_size, void* d_ws, size_t ws_size,
                              hipStream_t stream)
{
    (void)in_sizes; (void)n_in; (void)out_size; (void)ws_size;
    const float* x  = (const float*)d_in[0];
    const float* Wq = (const float*)d_in[1];
    const float* bq = (const float*)d_in[2];
    const float* Wk = (const float*)d_in[3];
    const float* bk = (const float*)d_in[4];
    const float* Wv = (const float*)d_in[5];
    const float* bv = (const float*)d_in[6];
    const float* gp = (const float*)d_in[7];
    const float* gc = (const float*)d_in[8];
    const float* gt = (const float*)d_in[9];
    float* out = (float*)d_out;
    float* ws  = (float*)d_ws;

    float* qbuf = ws;                          // [8][16][8192]   = 1,048,576
    float* kbuf = qbuf + 1048576;              // [8][16][8192]   = 1,048,576
    float* vbuf = kbuf + 1048576;              // [8][128][8192]  = 8,388,608
    float* Ebuf = vbuf + 8388608;              // [8][1024][1024] = 8,388,608
    float* part = Ebuf + 8388608;              // [8][32][128][128]=4,194,304
    float* acam = part + 4194304;              // [8][128][128]   = 131,072
    float* etim = acam + 131072;               // [8][64]
    float* atim = etim + 512;                  // [8][64]
    // total ws: ~23.2M floats = ~93 MB

    hipMemsetAsync(etim, 0, 512 * sizeof(float), stream);

    k_qkv        <<<dim3(128, 8),    256, 0, stream>>>(x, Wq, bq, Wk, bk, Wv, bv,
                                                       qbuf, kbuf, vbuf);
    k_energy     <<<dim3(16, 16, 8), 256, 0, stream>>>(qbuf, kbuf, Ebuf);
    k_softmax    <<<dim3(8192),      256, 0, stream>>>(Ebuf);
    k_pv         <<<dim3(8, 8, 8),   256, 0, stream>>>(vbuf, Ebuf, gp, out);
    k_cam_partial<<<dim3(32, 8),     256, 0, stream>>>(x, part);
    k_cam_reduce <<<dim3(128, 8),    128, 0, stream>>>(part, acam);
    k_tim_gram   <<<dim3(128, 8),    256, 0, stream>>>(x, etim);
    k_tim_softmax<<<dim3(1),         512, 0, stream>>>(etim, atim);
    k_final      <<<dim3(64, 8),     256, 0, stream>>>(x, acam, atim, gc, gt, out);
}

// Round 2
// 427.161 us; speedup vs baseline: 1.5032x; 1.5032x over previous
//
#include <hip/hip_runtime.h>
#include <cstdint>

typedef unsigned short u16;
typedef __attribute__((ext_vector_type(8))) short bf16x8;
typedef __attribute__((ext_vector_type(4))) float f32x4;

constexpr int B_  = 8;
constexpr int C_  = 128;
constexpr int CQ  = 16;
constexpr int T_  = 8;
constexpr int HW_ = 1024;
constexpr int P_  = T_ * HW_;   // 8192 positions per (b,c)
constexpr int F_  = CQ * T_;    // 128  PAM feature dim
constexpr int CT_ = C_ * T_;    // 1024

static __device__ __forceinline__ u16 f2bf(float f) {
    union { float f; unsigned u; } v; v.f = f;
    unsigned r = v.u + 0x7fffu + ((v.u >> 16) & 1u);   // RNE
    return (u16)(r >> 16);
}

#define GLOAD16(src, dst)                                                     \
    __builtin_amdgcn_global_load_lds(                                         \
        (const __attribute__((address_space(1))) void*)(src),                 \
        (__attribute__((address_space(3))) void*)(dst), 16, 0, 0)

// ---------------------------------------------------------------------------
// QKV 1x1x1 conv. Outputs: q_t,k_t bf16 [B][HW][128] (f = cq*8+t, K-contig),
// v bf16 [B][ct][m] (ct=c*8+t, m=hw). Block: 64 positions (one t), 160 oc.
// ---------------------------------------------------------------------------
__global__ __launch_bounds__(256)
void k_qkv(const float* __restrict__ x,
           const float* __restrict__ Wq, const float* __restrict__ bq,
           const float* __restrict__ Wk, const float* __restrict__ bk,
           const float* __restrict__ Wv, const float* __restrict__ bv,
           u16* __restrict__ qt, u16* __restrict__ kt, u16* __restrict__ v16)
{
    __shared__ float xs[128][64];
    const int b   = blockIdx.y;
    const int p0  = blockIdx.x * 64;
    const int t   = p0 >> 10;          // all 64 positions share one t
    const int hw0 = p0 & 1023;
    const int tid = threadIdx.x;

    #pragma unroll
    for (int r = 0; r < 8; r++) {
        int idx = r * 256 + tid;
        int c   = idx >> 4;
        int pj  = (idx & 15) << 2;
        *(float4*)&xs[c][pj] =
            *(const float4*)&x[((size_t)(b * C_ + c)) * P_ + p0 + pj];
    }
    __syncthreads();

    const int pq = (tid & 15) << 2;
    const int g  = tid >> 4;

    const float* wrow[10];
    float4       acc[10];
    #pragma unroll
    for (int j = 0; j < 10; j++) {
        int oc = g * 10 + j;
        float bias;
        if (oc < 16)      { wrow[j] = Wq + oc * C_;        bias = bq[oc]; }
        else if (oc < 32) { wrow[j] = Wk + (oc - 16) * C_; bias = bk[oc - 16]; }
        else              { wrow[j] = Wv + (oc - 32) * C_; bias = bv[oc - 32]; }
        acc[j] = make_float4(bias, bias, bias, bias);
    }

    for (int c4 = 0; c4 < 32; c4++) {
        float4 xv0 = *(float4*)&xs[c4 * 4 + 0][pq];
        float4 xv1 = *(float4*)&xs[c4 * 4 + 1][pq];
        float4 xv2 = *(float4*)&xs[c4 * 4 + 2][pq];
        float4 xv3 = *(float4*)&xs[c4 * 4 + 3][pq];
        #pragma unroll
        for (int j = 0; j < 10; j++) {
            float4 w = *(const float4*)&wrow[j][c4 * 4];
            acc[j].x += w.x * xv0.x + w.y * xv1.x + w.z * xv2.x + w.w * xv3.x;
            acc[j].y += w.x * xv0.y + w.y * xv1.y + w.z * xv2.y + w.w * xv3.y;
            acc[j].z += w.x * xv0.z + w.y * xv1.z + w.z * xv2.z + w.w * xv3.z;
            acc[j].w += w.x * xv0.w + w.y * xv1.w + w.z * xv2.w + w.w * xv3.w;
        }
    }

    #pragma unroll
    for (int j = 0; j < 10; j++) {
        int oc = g * 10 + j;
        float a4[4] = {acc[j].x, acc[j].y, acc[j].z, acc[j].w};
        if (oc < 16) {
            #pragma unroll
            for (int i = 0; i < 4; i++)
                qt[((size_t)b * HW_ + hw0 + pq + i) * F_ + oc * 8 + t] = f2bf(a4[i]);
        } else if (oc < 32) {
            #pragma unroll
            for (int i = 0; i < 4; i++)
                kt[((size_t)b * HW_ + hw0 + pq + i) * F_ + (oc - 16) * 8 + t] = f2bf(a4[i]);
        } else {
            ushort4 pk;
            pk.x = f2bf(a4[0]); pk.y = f2bf(a4[1]);
            pk.z = f2bf(a4[2]); pk.w = f2bf(a4[3]);
            *(ushort4*)&v16[((size_t)(b * C_ + oc - 32)) * P_ + p0 + pq] = pk;
        }
    }
}

// ---------------------------------------------------------------------------
// Energy MFMA: E[b][n][m] = sum_f qt[b][n][f] * kt[b][m][f].  K=128 one shot.
// 128x128 tile, 4 waves x (64x64). LDS rows 256B, XOR-swizzled slots.
// ---------------------------------------------------------------------------
__global__ __launch_bounds__(256)
void k_energy(const u16* __restrict__ qt, const u16* __restrict__ kt,
              float* __restrict__ E)
{
    __shared__ char As[32768];
    __shared__ char Bs[32768];
    const int b  = blockIdx.z;
    const int n0 = blockIdx.y * 128, m0 = blockIdx.x * 128;
    const int tid = threadIdx.x, lane = tid & 63, w = tid >> 6;
    const u16* qb = qt + (size_t)b * HW_ * F_;
    const u16* kb = kt + (size_t)b * HW_ * F_;

    // stage: chunk c = 4 rows x 256B (1KB per wave-instruction)
    #pragma unroll
    for (int i = 0; i < 8; i++) {
        int c    = w * 8 + i;                        // 0..31
        int row  = c * 4 + (lane >> 4);
        int col  = ((lane & 15) ^ (row & 7)) * 8;    // inverse-swizzled source
        GLOAD16(qb + (size_t)(n0 + row) * F_ + col, As + c * 1024);
        GLOAD16(kb + (size_t)(m0 + row) * F_ + col, Bs + c * 1024);
    }
    __syncthreads();

    const int wr = w >> 1, wc = w & 1;
    f32x4 acc[4][4];
    #pragma unroll
    for (int mi = 0; mi < 4; mi++)
        #pragma unroll
        for (int ni = 0; ni < 4; ni++) acc[mi][ni] = (f32x4){0.f, 0.f, 0.f, 0.f};

    #pragma unroll
    for (int ks = 0; ks < 4; ks++) {
        bf16x8 af[4], bg[4];
        #pragma unroll
        for (int mi = 0; mi < 4; mi++) {
            int row  = wr * 64 + mi * 16 + (lane & 15);
            int slot = (ks * 4 + (lane >> 4)) ^ (row & 7);
            af[mi] = *(const bf16x8*)(As + row * 256 + slot * 16);
            int rb  = wc * 64 + mi * 16 + (lane & 15);
            int sb  = (ks * 4 + (lane >> 4)) ^ (rb & 7);
            bg[mi] = *(const bf16x8*)(Bs + rb * 256 + sb * 16);
        }
        #pragma unroll
        for (int mi = 0; mi < 4; mi++)
            #pragma unroll
            for (int ni = 0; ni < 4; ni++)
                acc[mi][ni] = __builtin_amdgcn_mfma_f32_16x16x32_bf16(
                    af[mi], bg[ni], acc[mi][ni], 0, 0, 0);
    }

    float* Eb = E + (size_t)b * HW_ * HW_;
    #pragma unroll
    for (int mi = 0; mi < 4; mi++)
        #pragma unroll
        for (int ni = 0; ni < 4; ni++)
            #pragma unroll
            for (int r = 0; r < 4; r++)
                Eb[(size_t)(n0 + wr * 64 + mi * 16 + (lane >> 4) * 4 + r) * HW_
                   + m0 + wc * 64 + ni * 16 + (lane & 15)] = acc[mi][ni][r];
}

// ---------------------------------------------------------------------------
// Row softmax (fp32 in) -> bf16 attn out. One block per row of 1024.
// ---------------------------------------------------------------------------
__global__ __launch_bounds__(256)
void k_softmax(const float* __restrict__ E, u16* __restrict__ A16)
{
    const float* e = E + (size_t)blockIdx.x * HW_;
    const int tid = threadIdx.x;
    float4 v = ((const float4*)e)[tid];
    float m = fmaxf(fmaxf(v.x, v.y), fmaxf(v.z, v.w));
    #pragma unroll
    for (int off = 32; off; off >>= 1) m = fmaxf(m, __shfl_xor(m, off));
    __shared__ float s1[4], s2[4];
    if ((tid & 63) == 0) s1[tid >> 6] = m;
    __syncthreads();
    m = fmaxf(fmaxf(s1[0], s1[1]), fmaxf(s1[2], s1[3]));
    v.x = __expf(v.x - m); v.y = __expf(v.y - m);
    v.z = __expf(v.z - m); v.w = __expf(v.w - m);
    float s = v.x + v.y + v.z + v.w;
    #pragma unroll
    for (int off = 32; off; off >>= 1) s += __shfl_xor(s, off);
    if ((tid & 63) == 0) s2[tid >> 6] = s;
    __syncthreads();
    s = s2[0] + s2[1] + s2[2] + s2[3];
    float inv = 1.0f / s;
    ushort4 pk;
    pk.x = f2bf(v.x * inv); pk.y = f2bf(v.y * inv);
    pk.z = f2bf(v.z * inv); pk.w = f2bf(v.w * inv);
    ((ushort4*)(A16 + (size_t)blockIdx.x * HW_))[tid] = pk;
}

// ---------------------------------------------------------------------------
// PV MFMA: out[b][ct][n] = gp * sum_m V[ct][m] * attn[n][m].
// 128x128 tile, BK=64, 16 K-tiles. LDS rows 128B, XOR-swizzled slots.
// ---------------------------------------------------------------------------
__global__ __launch_bounds__(256)
void k_pv(const u16* __restrict__ v16, const u16* __restrict__ A16,
          const float* __restrict__ gamma_pam, float* __restrict__ out)
{
    __shared__ char As[16384];
    __shared__ char Bs[16384];
    const int b   = blockIdx.z;
    const int ct0 = blockIdx.y * 128, n0 = blockIdx.x * 128;
    const int tid = threadIdx.x, lane = tid & 63, w = tid >> 6;
    const u16* vb = v16 + (size_t)b * CT_ * HW_;
    const u16* ab = A16 + (size_t)b * HW_ * HW_;

    const int wr = w >> 1, wc = w & 1;
    f32x4 acc[4][4];
    #pragma unroll
    for (int mi = 0; mi < 4; mi++)
        #pragma unroll
        for (int ni = 0; ni < 4; ni++) acc[mi][ni] = (f32x4){0.f, 0.f, 0.f, 0.f};

    for (int mc = 0; mc < 1024; mc += 64) {
        #pragma unroll
        for (int i = 0; i < 4; i++) {
            int c   = w * 4 + i;                      // 0..15 chunk of 8 rows
            int row = c * 8 + (lane >> 3);
            int col = ((lane & 7) ^ (row & 7)) * 8;   // inverse-swizzled source
            GLOAD16(vb + (size_t)(ct0 + row) * HW_ + mc + col, As + c * 1024);
            GLOAD16(ab + (size_t)(n0  + row) * HW_ + mc + col, Bs + c * 1024);
        }
        __syncthreads();
        #pragma unroll
        for (int ks = 0; ks < 2; ks++) {
            bf16x8 af[4], bg[4];
            #pragma unroll
            for (int mi = 0; mi < 4; mi++) {
                int row  = wr * 64 + mi * 16 + (lane & 15);
                int slot = (ks * 4 + (lane >> 4)) ^ (row & 7);
                af[mi] = *(const bf16x8*)(As + row * 128 + slot * 16);
                int rb  = wc * 64 + mi * 16 + (lane & 15);
                int sb  = (ks * 4 + (lane >> 4)) ^ (rb & 7);
                bg[mi] = *(const bf16x8*)(Bs + rb * 128 + sb * 16);
            }
            #pragma unroll
            for (int mi = 0; mi < 4; mi++)
                #pragma unroll
                for (int ni = 0; ni < 4; ni++)
                    acc[mi][ni] = __builtin_amdgcn_mfma_f32_16x16x32_bf16(
                        af[mi], bg[ni], acc[mi][ni], 0, 0, 0);
        }
        __syncthreads();
    }

    const float gp = gamma_pam[0];
    float* ob = out + (size_t)b * CT_ * HW_;
    #pragma unroll
    for (int mi = 0; mi < 4; mi++)
        #pragma unroll
        for (int ni = 0; ni < 4; ni++)
            #pragma unroll
            for (int r = 0; r < 4; r++)
                ob[(size_t)(ct0 + wr * 64 + mi * 16 + (lane >> 4) * 4 + r) * HW_
                   + n0 + wc * 64 + ni * 16 + (lane & 15)] = gp * acc[mi][ni][r];
}

// ---------------------------------------------------------------------------
// CAM gram partials (fp32 — bf16 would put ±0.3 into softmax exponents)
// ---------------------------------------------------------------------------
__global__ __launch_bounds__(256)
void k_cam_partial(const float* __restrict__ x, float* __restrict__ part)
{
    __shared__ float xs[64][132];
    const int b = blockIdx.y, ch = blockIdx.x;
    const int tid = threadIdx.x;
    const int n0 = ch * 256;
    const float* xb = x + (size_t)b * C_ * P_;
    const int tc = (tid & 15) << 3, td = (tid >> 4) << 3;
    float acc[8][8] = {};

    for (int sp = 0; sp < 4; sp++) {
        #pragma unroll
        for (int r = 0; r < 8; r++) {
            int idx = r * 256 + tid;
            int c = idx >> 4, nj = (idx & 15) << 2;
            float4 xv = *(const float4*)&xb[(size_t)c * P_ + n0 + sp * 64 + nj];
            xs[nj + 0][c] = xv.x; xs[nj + 1][c] = xv.y;
            xs[nj + 2][c] = xv.z; xs[nj + 3][c] = xv.w;
        }
        __syncthreads();
        for (int n = 0; n < 64; n++) {
            float4 a0 = *(float4*)&xs[n][tc], a1 = *(float4*)&xs[n][tc + 4];
            float4 b0 = *(float4*)&xs[n][td], b1 = *(float4*)&xs[n][td + 4];
            float av[8] = {a0.x, a0.y, a0.z, a0.w, a1.x, a1.y, a1.z, a1.w};
            float bv[8] = {b0.x, b0.y, b0.z, b0.w, b1.x, b1.y, b1.z, b1.w};
            #pragma unroll
            for (int i = 0; i < 8; i++)
                #pragma unroll
                for (int j = 0; j < 8; j++)
                    acc[i][j] += av[i] * bv[j];
        }
        __syncthreads();
    }
    float* pb = part + ((size_t)(b * 32 + ch)) * C_ * C_;
    #pragma unroll
    for (int i = 0; i < 8; i++) {
        *(float4*)&pb[(size_t)(tc + i) * C_ + td] =
            make_float4(acc[i][0], acc[i][1], acc[i][2], acc[i][3]);
        *(float4*)&pb[(size_t)(tc + i) * C_ + td + 4] =
            make_float4(acc[i][4], acc[i][5], acc[i][6], acc[i][7]);
    }
}

__global__ __launch_bounds__(128)
void k_cam_reduce(const float* __restrict__ part, float* __restrict__ a_cam)
{
    const int b = blockIdx.y, c = blockIdx.x;
    const int d = threadIdx.x;
    float s = 0.f;
    for (int ch = 0; ch < 32; ch++)
        s += part[(((size_t)(b * 32 + ch)) * C_ + c) * C_ + d];
    float mn = s;
    #pragma unroll
    for (int off = 32; off; off >>= 1) mn = fminf(mn, __shfl_xor(mn, off));
    __shared__ float m1[2], m2[2];
    if ((d & 63) == 0) m1[d >> 6] = mn;
    __syncthreads();
    mn = fminf(m1[0], m1[1]);
    float p = __expf(mn - s);
    float sum = p;
    #pragma unroll
    for (int off = 32; off; off >>= 1) sum += __shfl_xor(sum, off);
    if ((d & 63) == 0) m2[d >> 6] = sum;
    __syncthreads();
    sum = m2[0] + m2[1];
    a_cam[((size_t)(b * C_ + c)) * C_ + d] = p / sum;
}

__global__ __launch_bounds__(256)
void k_tim_gram(const float* __restrict__ x, float* __restrict__ e_t)
{
    const int b = blockIdx.y, c = blockIdx.x;
    const int tid = threadIdx.x;
    const float* xb = x + ((size_t)(b * C_ + c)) * P_;
    float acc[8][8] = {};
    for (int r = 0; r < 4; r++) {
        int hw = r * 256 + tid;
        float xv[8];
        #pragma unroll
        for (int t = 0; t < 8; t++) xv[t] = xb[t * HW_ + hw];
        #pragma unroll
        for (int t = 0; t < 8; t++)
            #pragma unroll
            for (int s2 = 0; s2 < 8; s2++)
                acc[t][s2] += xv[t] * xv[s2];
    }
    __shared__ float sm[4][64];
    const int lane = tid & 63, wid = tid >> 6;
    #pragma unroll
    for (int u = 0; u < 64; u++) {
        float vv = acc[u >> 3][u & 7];
        #pragma unroll
        for (int off = 32; off; off >>= 1) vv += __shfl_xor(vv, off);
        if (lane == 0) sm[wid][u] = vv;
    }
    __syncthreads();
    if (tid < 64) {
        float vv = sm[0][tid] + sm[1][tid] + sm[2][tid] + sm[3][tid];
        atomicAdd(&e_t[b * 64 + tid], vv);
    }
}

__global__ __launch_bounds__(512)
void k_tim_softmax(const float* __restrict__ e_t, float* __restrict__ a_t)
{
    const int tid = threadIdx.x;
    float v = e_t[tid];
    float mn = v;
    #pragma unroll
    for (int off = 4; off; off >>= 1) mn = fminf(mn, __shfl_xor(mn, off, 8));
    float p = __expf(mn - v);
    float s = p;
    #pragma unroll
    for (int off = 4; off; off >>= 1) s += __shfl_xor(s, off, 8);
    a_t[tid] = p / s;
}

__global__ __launch_bounds__(256)
void k_final(const float* __restrict__ x, const float* __restrict__ a_cam,
             const float* __restrict__ a_t,
             const float* __restrict__ gamma_cam, const float* __restrict__ gamma_tim,
             float* __restrict__ out)
{
    __shared__ float xs[128][128];
    const int b   = blockIdx.y;
    const int hw0 = blockIdx.x * 16;
    const int tid = threadIdx.x;
    const float* xb = x + (size_t)b * C_ * P_;

    #pragma unroll
    for (int r = 0; r < 16; r++) {
        int idx = r * 256 + tid;
        int c = idx >> 5, t = (idx >> 2) & 7, j4 = (idx & 3) << 2;
        *(float4*)&xs[c][t * 16 + j4] =
            *(const float4*)&xb[(size_t)c * P_ + t * HW_ + hw0 + j4];
    }
    __syncthreads();

    const int pos = tid & 127, chh = tid >> 7;
    const int t = pos >> 4, hwi = pos & 15;
    const float* ab = a_cam + (size_t)b * C_ * C_;

    float at[8];
    #pragma unroll
    for (int s2 = 0; s2 < 8; s2++) at[s2] = a_t[b * 64 + t * 8 + s2];

    float accc[64];
    #pragma unroll
    for (int j = 0; j < 64; j++) accc[j] = 0.f;

    for (int d4 = 0; d4 < 128; d4 += 4) {
        float xv0 = xs[d4 + 0][pos], xv1 = xs[d4 + 1][pos];
        float xv2 = xs[d4 + 2][pos], xv3 = xs[d4 + 3][pos];
        #pragma unroll
        for (int j = 0; j < 64; j++) {
            float4 a4 = *(const float4*)&ab[(size_t)(chh * 64 + j) * C_ + d4];
            accc[j] += a4.x * xv0 + a4.y * xv1 + a4.z * xv2 + a4.w * xv3;
        }
    }

    const float gc = gamma_cam[0], gt = gamma_tim[0];
    float* ob = out + (size_t)b * C_ * P_;
    #pragma unroll
    for (int j = 0; j < 64; j++) {
        int c = chh * 64 + j;
        float tim = 0.f;
        #pragma unroll
        for (int s2 = 0; s2 < 8; s2++) tim += at[s2] * xs[c][s2 * 16 + hwi];
        size_t oi = (size_t)c * P_ + t * HW_ + hw0 + hwi;
        ob[oi] += gc * accc[j] + gt * tim + 3.0f * xs[c][pos];
    }
}

// ---------------------------------------------------------------------------
extern "C" void kernel_launch(void* const* d_in, const int* in_sizes, int n_in,
                              void* d_out, int out_size, void* d_ws, size_t ws_size,
                              hipStream_t stream)
{
    (void)in_sizes; (void)n_in; (void)out_size; (void)ws_size;
    const float* x  = (const float*)d_in[0];
    const float* Wq = (const float*)d_in[1];
    const float* bq = (const float*)d_in[2];
    const float* Wk = (const float*)d_in[3];
    const float* bk = (const float*)d_in[4];
    const float* Wv = (const float*)d_in[5];
    const float* bv = (const float*)d_in[6];
    const float* gp = (const float*)d_in[7];
    const float* gc = (const float*)d_in[8];
    const float* gt = (const float*)d_in[9];
    float* out = (float*)d_out;

    u16*   qtb  = (u16*)d_ws;                     // 1,048,576 u16 (2 MB)
    u16*   ktb  = qtb + 1048576;                  // 2 MB
    u16*   v16  = ktb + 1048576;                  // 8,388,608 u16 (16 MB)
    float* Ebuf = (float*)(v16 + 8388608);        // 8,388,608 f32 (32 MB)
    u16*   A16  = (u16*)(Ebuf + 8388608);         // 8,388,608 u16 (16 MB)
    float* part = (float*)(A16 + 8388608);        // 4,194,304 f32
    float* acam = part + 4194304;                 // 131,072 f32
    float* etim = acam + 131072;                  // 512
    float* atim = etim + 512;                     // 512

    hipMemsetAsync(etim, 0, 512 * sizeof(float), stream);

    k_qkv        <<<dim3(128, 8),  256, 0, stream>>>(x, Wq, bq, Wk, bk, Wv, bv,
                                                     qtb, ktb, v16);
    k_energy     <<<dim3(8, 8, 8), 256, 0, stream>>>(qtb, ktb, Ebuf);
    k_softmax    <<<dim3(8192),    256, 0, stream>>>(Ebuf, A16);
    k_pv         <<<dim3(8, 8, 8), 256, 0, stream>>>(v16, A16, gp, out);
    k_cam_partial<<<dim3(32, 8),   256, 0, stream>>>(x, part);
    k_cam_reduce <<<dim3(128, 8),  128, 0, stream>>>(part, acam);
    k_tim_gram   <<<dim3(128, 8),  256, 0, stream>>>(x, etim);
    k_tim_softmax<<<dim3(1),       512, 0, stream>>>(etim, atim);
    k_final      <<<dim3(64, 8),   256, 0, stream>>>(x, acam, atim, gc, gt, out);
}

// Round 3
// 322.609 us; speedup vs baseline: 1.9903x; 1.3241x over previous
//
#include <hip/hip_runtime.h>
#include <cstdint>

typedef unsigned short u16;
typedef __attribute__((ext_vector_type(8))) short bf16x8;
typedef __attribute__((ext_vector_type(4))) float f32x4;

constexpr int B_  = 8;
constexpr int C_  = 128;
constexpr int CQ  = 16;
constexpr int T_  = 8;
constexpr int HW_ = 1024;
constexpr int P_  = T_ * HW_;   // 8192 positions per (b,c)
constexpr int F_  = CQ * T_;    // 128  PAM feature dim
constexpr int CT_ = C_ * T_;    // 1024

static __device__ __forceinline__ u16 f2bf(float f) {
    union { float f; unsigned u; } v; v.f = f;
    unsigned r = v.u + 0x7fffu + ((v.u >> 16) & 1u);   // RNE
    return (u16)(r >> 16);
}

#define GLOAD16(src, dst)                                                     \
    __builtin_amdgcn_global_load_lds(                                         \
        (const __attribute__((address_space(1))) void*)(src),                 \
        (__attribute__((address_space(3))) void*)(dst), 16, 0, 0)

// ---------------------------------------------------------------------------
// QKV 1x1x1 conv. Outputs: q_t,k_t bf16 [B][HW][128] (f = cq*8+t, K-contig),
// v bf16 [B][ct][m] (ct=c*8+t, m=hw). Block: 64 positions (one t), 160 oc.
// ---------------------------------------------------------------------------
__global__ __launch_bounds__(256)
void k_qkv(const float* __restrict__ x,
           const float* __restrict__ Wq, const float* __restrict__ bq,
           const float* __restrict__ Wk, const float* __restrict__ bk,
           const float* __restrict__ Wv, const float* __restrict__ bv,
           u16* __restrict__ qt, u16* __restrict__ kt, u16* __restrict__ v16)
{
    __shared__ float xs[128][64];
    const int b   = blockIdx.y;
    const int p0  = blockIdx.x * 64;
    const int t   = p0 >> 10;          // all 64 positions share one t
    const int hw0 = p0 & 1023;
    const int tid = threadIdx.x;

    #pragma unroll
    for (int r = 0; r < 8; r++) {
        int idx = r * 256 + tid;
        int c   = idx >> 4;
        int pj  = (idx & 15) << 2;
        *(float4*)&xs[c][pj] =
            *(const float4*)&x[((size_t)(b * C_ + c)) * P_ + p0 + pj];
    }
    __syncthreads();

    const int pq = (tid & 15) << 2;
    const int g  = tid >> 4;

    const float* wrow[10];
    float4       acc[10];
    #pragma unroll
    for (int j = 0; j < 10; j++) {
        int oc = g * 10 + j;
        float bias;
        if (oc < 16)      { wrow[j] = Wq + oc * C_;        bias = bq[oc]; }
        else if (oc < 32) { wrow[j] = Wk + (oc - 16) * C_; bias = bk[oc - 16]; }
        else              { wrow[j] = Wv + (oc - 32) * C_; bias = bv[oc - 32]; }
        acc[j] = make_float4(bias, bias, bias, bias);
    }

    for (int c4 = 0; c4 < 32; c4++) {
        float4 xv0 = *(float4*)&xs[c4 * 4 + 0][pq];
        float4 xv1 = *(float4*)&xs[c4 * 4 + 1][pq];
        float4 xv2 = *(float4*)&xs[c4 * 4 + 2][pq];
        float4 xv3 = *(float4*)&xs[c4 * 4 + 3][pq];
        #pragma unroll
        for (int j = 0; j < 10; j++) {
            float4 w = *(const float4*)&wrow[j][c4 * 4];
            acc[j].x += w.x * xv0.x + w.y * xv1.x + w.z * xv2.x + w.w * xv3.x;
            acc[j].y += w.x * xv0.y + w.y * xv1.y + w.z * xv2.y + w.w * xv3.y;
            acc[j].z += w.x * xv0.z + w.y * xv1.z + w.z * xv2.z + w.w * xv3.z;
            acc[j].w += w.x * xv0.w + w.y * xv1.w + w.z * xv2.w + w.w * xv3.w;
        }
    }

    #pragma unroll
    for (int j = 0; j < 10; j++) {
        int oc = g * 10 + j;
        float a4[4] = {acc[j].x, acc[j].y, acc[j].z, acc[j].w};
        if (oc < 16) {
            #pragma unroll
            for (int i = 0; i < 4; i++)
                qt[((size_t)b * HW_ + hw0 + pq + i) * F_ + oc * 8 + t] = f2bf(a4[i]);
        } else if (oc < 32) {
            #pragma unroll
            for (int i = 0; i < 4; i++)
                kt[((size_t)b * HW_ + hw0 + pq + i) * F_ + (oc - 16) * 8 + t] = f2bf(a4[i]);
        } else {
            ushort4 pk;
            pk.x = f2bf(a4[0]); pk.y = f2bf(a4[1]);
            pk.z = f2bf(a4[2]); pk.w = f2bf(a4[3]);
            *(ushort4*)&v16[((size_t)(b * C_ + oc - 32)) * P_ + p0 + pq] = pk;
        }
    }
}

// ---------------------------------------------------------------------------
// Energy MFMA: E[b][n][m] = sum_f qt[b][n][f] * kt[b][m][f].  K=128 one shot.
// ---------------------------------------------------------------------------
__global__ __launch_bounds__(256)
void k_energy(const u16* __restrict__ qt, const u16* __restrict__ kt,
              float* __restrict__ E)
{
    __shared__ char As[32768];
    __shared__ char Bs[32768];
    const int b  = blockIdx.z;
    const int n0 = blockIdx.y * 128, m0 = blockIdx.x * 128;
    const int tid = threadIdx.x, lane = tid & 63, w = tid >> 6;
    const u16* qb = qt + (size_t)b * HW_ * F_;
    const u16* kb = kt + (size_t)b * HW_ * F_;

    #pragma unroll
    for (int i = 0; i < 8; i++) {
        int c    = w * 8 + i;
        int row  = c * 4 + (lane >> 4);
        int col  = ((lane & 15) ^ (row & 7)) * 8;
        GLOAD16(qb + (size_t)(n0 + row) * F_ + col, As + c * 1024);
        GLOAD16(kb + (size_t)(m0 + row) * F_ + col, Bs + c * 1024);
    }
    __syncthreads();

    const int wr = w >> 1, wc = w & 1;
    f32x4 acc[4][4];
    #pragma unroll
    for (int mi = 0; mi < 4; mi++)
        #pragma unroll
        for (int ni = 0; ni < 4; ni++) acc[mi][ni] = (f32x4){0.f, 0.f, 0.f, 0.f};

    #pragma unroll
    for (int ks = 0; ks < 4; ks++) {
        bf16x8 af[4], bg[4];
        #pragma unroll
        for (int mi = 0; mi < 4; mi++) {
            int row  = wr * 64 + mi * 16 + (lane & 15);
            int slot = (ks * 4 + (lane >> 4)) ^ (row & 7);
            af[mi] = *(const bf16x8*)(As + row * 256 + slot * 16);
            int rb  = wc * 64 + mi * 16 + (lane & 15);
            int sb  = (ks * 4 + (lane >> 4)) ^ (rb & 7);
            bg[mi] = *(const bf16x8*)(Bs + rb * 256 + sb * 16);
        }
        #pragma unroll
        for (int mi = 0; mi < 4; mi++)
            #pragma unroll
            for (int ni = 0; ni < 4; ni++)
                acc[mi][ni] = __builtin_amdgcn_mfma_f32_16x16x32_bf16(
                    af[mi], bg[ni], acc[mi][ni], 0, 0, 0);
    }

    float* Eb = E + (size_t)b * HW_ * HW_;
    #pragma unroll
    for (int mi = 0; mi < 4; mi++)
        #pragma unroll
        for (int ni = 0; ni < 4; ni++)
            #pragma unroll
            for (int r = 0; r < 4; r++)
                Eb[(size_t)(n0 + wr * 64 + mi * 16 + (lane >> 4) * 4 + r) * HW_
                   + m0 + wc * 64 + ni * 16 + (lane & 15)] = acc[mi][ni][r];
}

// ---------------------------------------------------------------------------
// Row softmax (fp32 in) -> bf16 attn out.
// ---------------------------------------------------------------------------
__global__ __launch_bounds__(256)
void k_softmax(const float* __restrict__ E, u16* __restrict__ A16)
{
    const float* e = E + (size_t)blockIdx.x * HW_;
    const int tid = threadIdx.x;
    float4 v = ((const float4*)e)[tid];
    float m = fmaxf(fmaxf(v.x, v.y), fmaxf(v.z, v.w));
    #pragma unroll
    for (int off = 32; off; off >>= 1) m = fmaxf(m, __shfl_xor(m, off));
    __shared__ float s1[4], s2[4];
    if ((tid & 63) == 0) s1[tid >> 6] = m;
    __syncthreads();
    m = fmaxf(fmaxf(s1[0], s1[1]), fmaxf(s1[2], s1[3]));
    v.x = __expf(v.x - m); v.y = __expf(v.y - m);
    v.z = __expf(v.z - m); v.w = __expf(v.w - m);
    float s = v.x + v.y + v.z + v.w;
    #pragma unroll
    for (int off = 32; off; off >>= 1) s += __shfl_xor(s, off);
    if ((tid & 63) == 0) s2[tid >> 6] = s;
    __syncthreads();
    s = s2[0] + s2[1] + s2[2] + s2[3];
    float inv = 1.0f / s;
    ushort4 pk;
    pk.x = f2bf(v.x * inv); pk.y = f2bf(v.y * inv);
    pk.z = f2bf(v.z * inv); pk.w = f2bf(v.w * inv);
    ((ushort4*)(A16 + (size_t)blockIdx.x * HW_))[tid] = pk;
}

// ---------------------------------------------------------------------------
// PV MFMA: out[b][ct][n] = gp * sum_m V[ct][m] * attn[n][m].
// ---------------------------------------------------------------------------
__global__ __launch_bounds__(256)
void k_pv(const u16* __restrict__ v16, const u16* __restrict__ A16,
          const float* __restrict__ gamma_pam, float* __restrict__ out)
{
    __shared__ char As[16384];
    __shared__ char Bs[16384];
    const int b   = blockIdx.z;
    const int ct0 = blockIdx.y * 128, n0 = blockIdx.x * 128;
    const int tid = threadIdx.x, lane = tid & 63, w = tid >> 6;
    const u16* vb = v16 + (size_t)b * CT_ * HW_;
    const u16* ab = A16 + (size_t)b * HW_ * HW_;

    const int wr = w >> 1, wc = w & 1;
    f32x4 acc[4][4];
    #pragma unroll
    for (int mi = 0; mi < 4; mi++)
        #pragma unroll
        for (int ni = 0; ni < 4; ni++) acc[mi][ni] = (f32x4){0.f, 0.f, 0.f, 0.f};

    for (int mc = 0; mc < 1024; mc += 64) {
        #pragma unroll
        for (int i = 0; i < 4; i++) {
            int c   = w * 4 + i;
            int row = c * 8 + (lane >> 3);
            int col = ((lane & 7) ^ (row & 7)) * 8;
            GLOAD16(vb + (size_t)(ct0 + row) * HW_ + mc + col, As + c * 1024);
            GLOAD16(ab + (size_t)(n0  + row) * HW_ + mc + col, Bs + c * 1024);
        }
        __syncthreads();
        #pragma unroll
        for (int ks = 0; ks < 2; ks++) {
            bf16x8 af[4], bg[4];
            #pragma unroll
            for (int mi = 0; mi < 4; mi++) {
                int row  = wr * 64 + mi * 16 + (lane & 15);
                int slot = (ks * 4 + (lane >> 4)) ^ (row & 7);
                af[mi] = *(const bf16x8*)(As + row * 128 + slot * 16);
                int rb  = wc * 64 + mi * 16 + (lane & 15);
                int sb  = (ks * 4 + (lane >> 4)) ^ (rb & 7);
                bg[mi] = *(const bf16x8*)(Bs + rb * 128 + sb * 16);
            }
            #pragma unroll
            for (int mi = 0; mi < 4; mi++)
                #pragma unroll
                for (int ni = 0; ni < 4; ni++)
                    acc[mi][ni] = __builtin_amdgcn_mfma_f32_16x16x32_bf16(
                        af[mi], bg[ni], acc[mi][ni], 0, 0, 0);
        }
        __syncthreads();
    }

    const float gp = gamma_pam[0];
    float* ob = out + (size_t)b * CT_ * HW_;
    #pragma unroll
    for (int mi = 0; mi < 4; mi++)
        #pragma unroll
        for (int ni = 0; ni < 4; ni++)
            #pragma unroll
            for (int r = 0; r < 4; r++)
                ob[(size_t)(ct0 + wr * 64 + mi * 16 + (lane >> 4) * 4 + r) * HW_
                   + n0 + wc * 64 + ni * 16 + (lane & 15)] = gp * acc[mi][ni][r];
}

// ---------------------------------------------------------------------------
// CAM gram partials (fp32)
// ---------------------------------------------------------------------------
__global__ __launch_bounds__(256)
void k_cam_partial(const float* __restrict__ x, float* __restrict__ part)
{
    __shared__ float xs[64][132];
    const int b = blockIdx.y, ch = blockIdx.x;
    const int tid = threadIdx.x;
    const int n0 = ch * 256;
    const float* xb = x + (size_t)b * C_ * P_;
    const int tc = (tid & 15) << 3, td = (tid >> 4) << 3;
    float acc[8][8] = {};

    for (int sp = 0; sp < 4; sp++) {
        #pragma unroll
        for (int r = 0; r < 8; r++) {
            int idx = r * 256 + tid;
            int c = idx >> 4, nj = (idx & 15) << 2;
            float4 xv = *(const float4*)&xb[(size_t)c * P_ + n0 + sp * 64 + nj];
            xs[nj + 0][c] = xv.x; xs[nj + 1][c] = xv.y;
            xs[nj + 2][c] = xv.z; xs[nj + 3][c] = xv.w;
        }
        __syncthreads();
        for (int n = 0; n < 64; n++) {
            float4 a0 = *(float4*)&xs[n][tc], a1 = *(float4*)&xs[n][tc + 4];
            float4 b0 = *(float4*)&xs[n][td], b1 = *(float4*)&xs[n][td + 4];
            float av[8] = {a0.x, a0.y, a0.z, a0.w, a1.x, a1.y, a1.z, a1.w};
            float bv[8] = {b0.x, b0.y, b0.z, b0.w, b1.x, b1.y, b1.z, b1.w};
            #pragma unroll
            for (int i = 0; i < 8; i++)
                #pragma unroll
                for (int j = 0; j < 8; j++)
                    acc[i][j] += av[i] * bv[j];
        }
        __syncthreads();
    }
    float* pb = part + ((size_t)(b * 32 + ch)) * C_ * C_;
    #pragma unroll
    for (int i = 0; i < 8; i++) {
        *(float4*)&pb[(size_t)(tc + i) * C_ + td] =
            make_float4(acc[i][0], acc[i][1], acc[i][2], acc[i][3]);
        *(float4*)&pb[(size_t)(tc + i) * C_ + td + 4] =
            make_float4(acc[i][4], acc[i][5], acc[i][6], acc[i][7]);
    }
}

// ---------------------------------------------------------------------------
// CAM reduce + negated softmax -> bf16, pre-scaled by gamma_cam.
// ---------------------------------------------------------------------------
__global__ __launch_bounds__(128)
void k_cam_reduce(const float* __restrict__ part,
                  const float* __restrict__ gamma_cam, u16* __restrict__ acam16)
{
    const int b = blockIdx.y, c = blockIdx.x;
    const int d = threadIdx.x;
    float s = 0.f;
    for (int ch = 0; ch < 32; ch++)
        s += part[(((size_t)(b * 32 + ch)) * C_ + c) * C_ + d];
    float mn = s;
    #pragma unroll
    for (int off = 32; off; off >>= 1) mn = fminf(mn, __shfl_xor(mn, off));
    __shared__ float m1[2], m2[2];
    if ((d & 63) == 0) m1[d >> 6] = mn;
    __syncthreads();
    mn = fminf(m1[0], m1[1]);
    float p = __expf(mn - s);
    float sum = p;
    #pragma unroll
    for (int off = 32; off; off >>= 1) sum += __shfl_xor(sum, off);
    if ((d & 63) == 0) m2[d >> 6] = sum;
    __syncthreads();
    sum = m2[0] + m2[1];
    acam16[((size_t)(b * C_ + c)) * C_ + d] = f2bf(gamma_cam[0] * p / sum);
}

__global__ __launch_bounds__(256)
void k_tim_gram(const float* __restrict__ x, float* __restrict__ e_t)
{
    const int b = blockIdx.y, c = blockIdx.x;
    const int tid = threadIdx.x;
    const float* xb = x + ((size_t)(b * C_ + c)) * P_;
    float acc[8][8] = {};
    for (int r = 0; r < 4; r++) {
        int hw = r * 256 + tid;
        float xv[8];
        #pragma unroll
        for (int t = 0; t < 8; t++) xv[t] = xb[t * HW_ + hw];
        #pragma unroll
        for (int t = 0; t < 8; t++)
            #pragma unroll
            for (int s2 = 0; s2 < 8; s2++)
                acc[t][s2] += xv[t] * xv[s2];
    }
    __shared__ float sm[4][64];
    const int lane = tid & 63, wid = tid >> 6;
    #pragma unroll
    for (int u = 0; u < 64; u++) {
        float vv = acc[u >> 3][u & 7];
        #pragma unroll
        for (int off = 32; off; off >>= 1) vv += __shfl_xor(vv, off);
        if (lane == 0) sm[wid][u] = vv;
    }
    __syncthreads();
    if (tid < 64) {
        float vv = sm[0][tid] + sm[1][tid] + sm[2][tid] + sm[3][tid];
        atomicAdd(&e_t[b * 64 + tid], vv);
    }
}

__global__ __launch_bounds__(512)
void k_tim_softmax(const float* __restrict__ e_t, float* __restrict__ a_t)
{
    const int tid = threadIdx.x;
    float v = e_t[tid];
    float mn = v;
    #pragma unroll
    for (int off = 4; off; off >>= 1) mn = fminf(mn, __shfl_xor(mn, off, 8));
    float p = __expf(mn - v);
    float s = p;
    #pragma unroll
    for (int off = 4; off; off >>= 1) s += __shfl_xor(s, off, 8);
    a_t[tid] = p / s;
}

// ---------------------------------------------------------------------------
// X' = 3x + gt * (TIM t-mix of x), fp32. Block: one (b,c) row, 8192 elems.
// ---------------------------------------------------------------------------
__global__ __launch_bounds__(256)
void k_xprime(const float* __restrict__ x, const float* __restrict__ atim,
              const float* __restrict__ gamma_tim, float* __restrict__ Xp)
{
    const int b = blockIdx.y, c = blockIdx.x;
    const size_t base = ((size_t)(b * C_ + c)) * P_;
    const int tid = threadIdx.x;
    const float gt = gamma_tim[0];

    float4 xv[8];
    #pragma unroll
    for (int t = 0; t < 8; t++)
        xv[t] = *(const float4*)&x[base + t * HW_ + tid * 4];

    #pragma unroll
    for (int t = 0; t < 8; t++) {
        float4 o = make_float4(3.f * xv[t].x, 3.f * xv[t].y,
                               3.f * xv[t].z, 3.f * xv[t].w);
        #pragma unroll
        for (int s = 0; s < 8; s++) {
            float w = gt * atim[b * 64 + t * 8 + s];
            o.x += w * xv[s].x; o.y += w * xv[s].y;
            o.z += w * xv[s].z; o.w += w * xv[s].w;
        }
        *(float4*)&Xp[base + t * HW_ + tid * 4] = o;
    }
}

// ---------------------------------------------------------------------------
// Transpose-cast: xT[b][p][c] = bf16(x[b][c][p]). 128x128 LDS tile, XOR-swz.
// ---------------------------------------------------------------------------
__global__ __launch_bounds__(256)
void k_xt(const float* __restrict__ x, u16* __restrict__ xT)
{
    __shared__ char sy[32768];
    const int b  = blockIdx.y;
    const int p0 = blockIdx.x * 128;
    const int tid = threadIdx.x;

    #pragma unroll
    for (int r = 0; r < 16; r++) {
        int lin = r * 256 + tid;
        int c = lin >> 5, j4 = (lin & 31) << 2;
        float4 xv = *(const float4*)&x[((size_t)(b * C_ + c)) * P_ + p0 + j4];
        float a4[4] = {xv.x, xv.y, xv.z, xv.w};
        #pragma unroll
        for (int u = 0; u < 4; u++) {
            int pi = j4 + u;
            int byte = pi * 256 + ((c * 2) ^ (((pi >> 2) & 15) << 4));
            *(u16*)(sy + byte) = f2bf(a4[u]);
        }
    }
    __syncthreads();
    #pragma unroll
    for (int r = 0; r < 8; r++) {
        int lin = r * 256 + tid;
        int pi = lin >> 4, ci8 = (lin & 15) << 3;
        bf16x8 v = *(const bf16x8*)(sy + pi * 256 +
                                    ((ci8 * 2) ^ (((pi >> 2) & 15) << 4)));
        *(bf16x8*)&xT[((size_t)(b * P_ + p0 + pi)) * C_ + ci8] = v;
    }
}

// ---------------------------------------------------------------------------
// CAM AV MFMA + fused epilogue: out += acam16 @ x  + X'.
// M=128(c), N=8192(p), K=128(d). No LDS: A (L2-hot) and B (xT) direct frags.
// ---------------------------------------------------------------------------
__global__ __launch_bounds__(256)
void k_cam_av(const u16* __restrict__ acam16, const u16* __restrict__ xT,
              const float* __restrict__ Xp, float* __restrict__ out)
{
    const int b  = blockIdx.y;
    const int p0 = blockIdx.x * 128;
    const int tid = threadIdx.x, lane = tid & 63, w = tid >> 6;

    const u16* Ab = acam16 + (size_t)b * C_ * C_;
    const u16* Bb = xT + ((size_t)(b * P_ + p0 + w * 32)) * C_;

    f32x4 acc[8][2];
    #pragma unroll
    for (int mi = 0; mi < 8; mi++) {
        acc[mi][0] = (f32x4){0.f, 0.f, 0.f, 0.f};
        acc[mi][1] = (f32x4){0.f, 0.f, 0.f, 0.f};
    }

    bf16x8 bg[4][2];
    #pragma unroll
    for (int ks = 0; ks < 4; ks++)
        #pragma unroll
        for (int ni = 0; ni < 2; ni++)
            bg[ks][ni] = *(const bf16x8*)(Bb +
                (size_t)(ni * 16 + (lane & 15)) * C_ + ks * 32 + (lane >> 4) * 8);

    #pragma unroll
    for (int mi = 0; mi < 8; mi++) {
        #pragma unroll
        for (int ks = 0; ks < 4; ks++) {
            bf16x8 af = *(const bf16x8*)(Ab +
                (size_t)(mi * 16 + (lane & 15)) * C_ + ks * 32 + (lane >> 4) * 8);
            acc[mi][0] = __builtin_amdgcn_mfma_f32_16x16x32_bf16(
                af, bg[ks][0], acc[mi][0], 0, 0, 0);
            acc[mi][1] = __builtin_amdgcn_mfma_f32_16x16x32_bf16(
                af, bg[ks][1], acc[mi][1], 0, 0, 0);
        }
    }

    float* ob = out + (size_t)b * C_ * P_;
    const float* xp = Xp + (size_t)b * C_ * P_;
    #pragma unroll
    for (int mi = 0; mi < 8; mi++)
        #pragma unroll
        for (int ni = 0; ni < 2; ni++)
            #pragma unroll
            for (int r = 0; r < 4; r++) {
                int c = mi * 16 + (lane >> 4) * 4 + r;
                int p = p0 + w * 32 + ni * 16 + (lane & 15);
                size_t i = (size_t)c * P_ + p;
                ob[i] += acc[mi][ni][r] + xp[i];
            }
}

// ---------------------------------------------------------------------------
extern "C" void kernel_launch(void* const* d_in, const int* in_sizes, int n_in,
                              void* d_out, int out_size, void* d_ws, size_t ws_size,
                              hipStream_t stream)
{
    (void)in_sizes; (void)n_in; (void)out_size; (void)ws_size;
    const float* x  = (const float*)d_in[0];
    const float* Wq = (const float*)d_in[1];
    const float* bq = (const float*)d_in[2];
    const float* Wk = (const float*)d_in[3];
    const float* bk = (const float*)d_in[4];
    const float* Wv = (const float*)d_in[5];
    const float* bv = (const float*)d_in[6];
    const float* gp = (const float*)d_in[7];
    const float* gc = (const float*)d_in[8];
    const float* gt = (const float*)d_in[9];
    float* out = (float*)d_out;
    char*  ws  = (char*)d_ws;

    // byte layout (aliased regions noted)
    u16*   qtb    = (u16*)(ws + 0);               // 2 MB
    u16*   ktb    = (u16*)(ws + (2u << 20));      // 2 MB
    u16*   v16    = (u16*)(ws + (4u << 20));      // 16 MB; reused as part
    float* part   = (float*)(ws + (4u << 20));
    float* Ebuf   = (float*)(ws + (20u << 20));   // 32 MB; reused as Xp
    float* Xp     = (float*)(ws + (20u << 20));
    u16*   A16    = (u16*)(ws + (52u << 20));     // 16 MB; reused as xT
    u16*   xT     = (u16*)(ws + (52u << 20));
    u16*   acam16 = (u16*)(ws + (68u << 20));     // 32 KB
    float* etim   = (float*)(ws + (68u << 20) + 32768);
    float* atim   = etim + 512;

    hipMemsetAsync(etim, 0, 512 * sizeof(float), stream);

    k_qkv        <<<dim3(128, 8),  256, 0, stream>>>(x, Wq, bq, Wk, bk, Wv, bv,
                                                     qtb, ktb, v16);
    k_energy     <<<dim3(8, 8, 8), 256, 0, stream>>>(qtb, ktb, Ebuf);
    k_softmax    <<<dim3(8192),    256, 0, stream>>>(Ebuf, A16);
    k_tim_gram   <<<dim3(128, 8),  256, 0, stream>>>(x, etim);
    k_tim_softmax<<<dim3(1),       512, 0, stream>>>(etim, atim);
    k_pv         <<<dim3(8, 8, 8), 256, 0, stream>>>(v16, A16, gp, out);
    // v16/A16/Ebuf dead beyond this point -> aliases become live
    k_xprime     <<<dim3(128, 8),  256, 0, stream>>>(x, atim, gt, Xp);
    k_xt         <<<dim3(64, 8),   256, 0, stream>>>(x, xT);
    k_cam_partial<<<dim3(32, 8),   256, 0, stream>>>(x, part);
    k_cam_reduce <<<dim3(128, 8),  128, 0, stream>>>(part, gc, acam16);
    k_cam_av     <<<dim3(64, 8),   256, 0, stream>>>(acam16, xT, Xp, out);
}

// Round 4
// 263.369 us; speedup vs baseline: 2.4380x; 1.2249x over previous
//
#include <hip/hip_runtime.h>
#include <cstdint>

typedef unsigned short u16;
typedef __attribute__((ext_vector_type(8))) short bf16x8;
typedef __attribute__((ext_vector_type(4))) float f32x4;

constexpr int B_  = 8;
constexpr int C_  = 128;
constexpr int T_  = 8;
constexpr int HW_ = 1024;
constexpr int P_  = T_ * HW_;   // 8192 positions per (b,c)
constexpr int F_  = 128;        // PAM feature dim (16 cq * 8 t)
constexpr int CT_ = C_ * T_;    // 1024

static __device__ __forceinline__ u16 f2bf(float f) {
    union { float f; unsigned u; } v; v.f = f;
    unsigned r = v.u + 0x7fffu + ((v.u >> 16) & 1u);   // RNE
    return (u16)(r >> 16);
}
static __device__ __forceinline__ float bf2f(u16 h) {
    union { unsigned u; float f; } v; v.u = ((unsigned)h) << 16;
    return v.f;
}

#define GLOAD16(src, dst)                                                     \
    __builtin_amdgcn_global_load_lds(                                         \
        (const __attribute__((address_space(1))) void*)(src),                 \
        (__attribute__((address_space(3))) void*)(dst), 16, 0, 0)

// ---------------------------------------------------------------------------
// Cast Wq/Wk/Wv -> Wall[160][128] bf16, biases -> ball[160] fp32.
// ---------------------------------------------------------------------------
__global__ __launch_bounds__(256)
void k_wcast(const float* __restrict__ Wq, const float* __restrict__ bq,
             const float* __restrict__ Wk, const float* __restrict__ bk,
             const float* __restrict__ Wv, const float* __restrict__ bv,
             u16* __restrict__ Wall, float* __restrict__ ball)
{
    int tid = blockIdx.x * 256 + threadIdx.x;
    if (tid < 20480) {
        int oc = tid >> 7, c = tid & 127;
        float w;
        if (oc < 16)      w = Wq[oc * 128 + c];
        else if (oc < 32) w = Wk[(oc - 16) * 128 + c];
        else              w = Wv[(oc - 32) * 128 + c];
        Wall[tid] = f2bf(w);
    }
    if (tid < 160) {
        float bb;
        if (tid < 16)      bb = bq[tid];
        else if (tid < 32) bb = bk[tid - 16];
        else               bb = bv[tid - 32];
        ball[tid] = bb;
    }
}

// ---------------------------------------------------------------------------
// Transpose-cast: xT[b][p][c] = bf16(x[b][c][p]). 128x128 LDS tile, XOR-swz.
// ---------------------------------------------------------------------------
__global__ __launch_bounds__(256)
void k_prep(const float* __restrict__ x, u16* __restrict__ xT)
{
    __shared__ char sy[32768];
    const int b  = blockIdx.y;
    const int p0 = blockIdx.x * 128;
    const int tid = threadIdx.x;

    #pragma unroll
    for (int r = 0; r < 16; r++) {
        int lin = r * 256 + tid;
        int c = lin >> 5, j4 = (lin & 31) << 2;
        float4 xv = *(const float4*)&x[((size_t)(b * C_ + c)) * P_ + p0 + j4];
        float a4[4] = {xv.x, xv.y, xv.z, xv.w};
        #pragma unroll
        for (int u = 0; u < 4; u++) {
            int pi = j4 + u;
            int byte = pi * 256 + ((c * 2) ^ (((pi >> 2) & 15) << 4));
            *(u16*)(sy + byte) = f2bf(a4[u]);
        }
    }
    __syncthreads();
    #pragma unroll
    for (int r = 0; r < 8; r++) {
        int lin = r * 256 + tid;
        int pi = lin >> 4, ci8 = (lin & 15) << 3;
        bf16x8 v = *(const bf16x8*)(sy + pi * 256 +
                                    ((ci8 * 2) ^ (((pi >> 2) & 15) << 4)));
        *(bf16x8*)&xT[((size_t)(b * P_ + p0 + pi)) * C_ + ci8] = v;
    }
}

// ---------------------------------------------------------------------------
// QKV via MFMA: out[oc][p] = Wall[oc][:] . xT[p][:] + ball[oc].
// Block: 128 positions (one t), M=160 full. A staged in LDS (swizzled).
// ---------------------------------------------------------------------------
__global__ __launch_bounds__(256)
void k_qkv(const u16* __restrict__ xT, const u16* __restrict__ Wall,
           const float* __restrict__ ball,
           u16* __restrict__ qt, u16* __restrict__ kt, u16* __restrict__ v16)
{
    __shared__ char Ws[40960];                 // 160 rows x 256B
    const int b  = blockIdx.y;
    const int p0 = blockIdx.x * 128;
    const int tid = threadIdx.x, lane = tid & 63, w = tid >> 6;

    #pragma unroll
    for (int i = 0; i < 10; i++) {
        int ch  = w * 10 + i;                  // 0..39, 4 rows each
        int row = ch * 4 + (lane >> 4);
        int col = ((lane & 15) ^ (row & 7)) * 8;
        GLOAD16(Wall + row * 128 + col, Ws + ch * 1024);
    }

    const u16* Bb = xT + ((size_t)(b * P_ + p0 + w * 32)) * F_;
    bf16x8 bg[4][2];
    #pragma unroll
    for (int ks = 0; ks < 4; ks++)
        #pragma unroll
        for (int ni = 0; ni < 2; ni++)
            bg[ks][ni] = *(const bf16x8*)(Bb +
                (size_t)(ni * 16 + (lane & 15)) * F_ + ks * 32 + (lane >> 4) * 8);
    __syncthreads();

    f32x4 acc[10][2];
    #pragma unroll
    for (int mi = 0; mi < 10; mi++) {
        acc[mi][0] = (f32x4){0.f, 0.f, 0.f, 0.f};
        acc[mi][1] = (f32x4){0.f, 0.f, 0.f, 0.f};
    }

    #pragma unroll
    for (int mi = 0; mi < 10; mi++) {
        #pragma unroll
        for (int ks = 0; ks < 4; ks++) {
            int row  = mi * 16 + (lane & 15);
            int slot = (ks * 4 + (lane >> 4)) ^ (row & 7);
            bf16x8 af = *(const bf16x8*)(Ws + row * 256 + slot * 16);
            acc[mi][0] = __builtin_amdgcn_mfma_f32_16x16x32_bf16(
                af, bg[ks][0], acc[mi][0], 0, 0, 0);
            acc[mi][1] = __builtin_amdgcn_mfma_f32_16x16x32_bf16(
                af, bg[ks][1], acc[mi][1], 0, 0, 0);
        }
    }

    const int t      = p0 >> 10;
    const int hwbase = (p0 & 1023) + w * 32;
    #pragma unroll
    for (int mi = 0; mi < 10; mi++)
        #pragma unroll
        for (int ni = 0; ni < 2; ni++)
            #pragma unroll
            for (int r = 0; r < 4; r++) {
                int oc = mi * 16 + (lane >> 4) * 4 + r;
                int hw = hwbase + ni * 16 + (lane & 15);
                u16 bv16 = f2bf(acc[mi][ni][r] + ball[oc]);
                if (mi == 0)
                    qt[((size_t)b * HW_ + hw) * F_ + oc * 8 + t] = bv16;
                else if (mi == 1)
                    kt[((size_t)b * HW_ + hw) * F_ + (oc - 16) * 8 + t] = bv16;
                else
                    v16[((size_t)(b * C_ + oc - 32)) * P_ + t * HW_ + hw] = bv16;
            }
}

// ---------------------------------------------------------------------------
// Energy MFMA: E[b][n][m] = sum_f qt[b][n][f] * kt[b][m][f].  K=128 one shot.
// ---------------------------------------------------------------------------
__global__ __launch_bounds__(256)
void k_energy(const u16* __restrict__ qt, const u16* __restrict__ kt,
              float* __restrict__ E)
{
    __shared__ char As[32768];
    __shared__ char Bs[32768];
    const int b  = blockIdx.z;
    const int n0 = blockIdx.y * 128, m0 = blockIdx.x * 128;
    const int tid = threadIdx.x, lane = tid & 63, w = tid >> 6;
    const u16* qb = qt + (size_t)b * HW_ * F_;
    const u16* kb = kt + (size_t)b * HW_ * F_;

    #pragma unroll
    for (int i = 0; i < 8; i++) {
        int c    = w * 8 + i;
        int row  = c * 4 + (lane >> 4);
        int col  = ((lane & 15) ^ (row & 7)) * 8;
        GLOAD16(qb + (size_t)(n0 + row) * F_ + col, As + c * 1024);
        GLOAD16(kb + (size_t)(m0 + row) * F_ + col, Bs + c * 1024);
    }
    __syncthreads();

    const int wr = w >> 1, wc = w & 1;
    f32x4 acc[4][4];
    #pragma unroll
    for (int mi = 0; mi < 4; mi++)
        #pragma unroll
        for (int ni = 0; ni < 4; ni++) acc[mi][ni] = (f32x4){0.f, 0.f, 0.f, 0.f};

    #pragma unroll
    for (int ks = 0; ks < 4; ks++) {
        bf16x8 af[4], bg[4];
        #pragma unroll
        for (int mi = 0; mi < 4; mi++) {
            int row  = wr * 64 + mi * 16 + (lane & 15);
            int slot = (ks * 4 + (lane >> 4)) ^ (row & 7);
            af[mi] = *(const bf16x8*)(As + row * 256 + slot * 16);
            int rb  = wc * 64 + mi * 16 + (lane & 15);
            int sb  = (ks * 4 + (lane >> 4)) ^ (rb & 7);
            bg[mi] = *(const bf16x8*)(Bs + rb * 256 + sb * 16);
        }
        #pragma unroll
        for (int mi = 0; mi < 4; mi++)
            #pragma unroll
            for (int ni = 0; ni < 4; ni++)
                acc[mi][ni] = __builtin_amdgcn_mfma_f32_16x16x32_bf16(
                    af[mi], bg[ni], acc[mi][ni], 0, 0, 0);
    }

    float* Eb = E + (size_t)b * HW_ * HW_;
    #pragma unroll
    for (int mi = 0; mi < 4; mi++)
        #pragma unroll
        for (int ni = 0; ni < 4; ni++)
            #pragma unroll
            for (int r = 0; r < 4; r++)
                Eb[(size_t)(n0 + wr * 64 + mi * 16 + (lane >> 4) * 4 + r) * HW_
                   + m0 + wc * 64 + ni * 16 + (lane & 15)] = acc[mi][ni][r];
}

// ---------------------------------------------------------------------------
// Row softmax (fp32 in) -> bf16 attn out.
// ---------------------------------------------------------------------------
__global__ __launch_bounds__(256)
void k_softmax(const float* __restrict__ E, u16* __restrict__ A16)
{
    const float* e = E + (size_t)blockIdx.x * HW_;
    const int tid = threadIdx.x;
    float4 v = ((const float4*)e)[tid];
    float m = fmaxf(fmaxf(v.x, v.y), fmaxf(v.z, v.w));
    #pragma unroll
    for (int off = 32; off; off >>= 1) m = fmaxf(m, __shfl_xor(m, off));
    __shared__ float s1[4], s2[4];
    if ((tid & 63) == 0) s1[tid >> 6] = m;
    __syncthreads();
    m = fmaxf(fmaxf(s1[0], s1[1]), fmaxf(s1[2], s1[3]));
    v.x = __expf(v.x - m); v.y = __expf(v.y - m);
    v.z = __expf(v.z - m); v.w = __expf(v.w - m);
    float s = v.x + v.y + v.z + v.w;
    #pragma unroll
    for (int off = 32; off; off >>= 1) s += __shfl_xor(s, off);
    if ((tid & 63) == 0) s2[tid >> 6] = s;
    __syncthreads();
    s = s2[0] + s2[1] + s2[2] + s2[3];
    float inv = 1.0f / s;
    ushort4 pk;
    pk.x = f2bf(v.x * inv); pk.y = f2bf(v.y * inv);
    pk.z = f2bf(v.z * inv); pk.w = f2bf(v.w * inv);
    ((ushort4*)(A16 + (size_t)blockIdx.x * HW_))[tid] = pk;
}

// ---------------------------------------------------------------------------
// PV MFMA: out[b][ct][n] = gp * sum_m V[ct][m] * attn[n][m].
// ---------------------------------------------------------------------------
__global__ __launch_bounds__(256)
void k_pv(const u16* __restrict__ v16, const u16* __restrict__ A16,
          const float* __restrict__ gamma_pam, float* __restrict__ out)
{
    __shared__ char As[16384];
    __shared__ char Bs[16384];
    const int b   = blockIdx.z;
    const int ct0 = blockIdx.y * 128, n0 = blockIdx.x * 128;
    const int tid = threadIdx.x, lane = tid & 63, w = tid >> 6;
    const u16* vb = v16 + (size_t)b * CT_ * HW_;
    const u16* ab = A16 + (size_t)b * HW_ * HW_;

    const int wr = w >> 1, wc = w & 1;
    f32x4 acc[4][4];
    #pragma unroll
    for (int mi = 0; mi < 4; mi++)
        #pragma unroll
        for (int ni = 0; ni < 4; ni++) acc[mi][ni] = (f32x4){0.f, 0.f, 0.f, 0.f};

    for (int mc = 0; mc < 1024; mc += 64) {
        #pragma unroll
        for (int i = 0; i < 4; i++) {
            int c   = w * 4 + i;
            int row = c * 8 + (lane >> 3);
            int col = ((lane & 7) ^ (row & 7)) * 8;
            GLOAD16(vb + (size_t)(ct0 + row) * HW_ + mc + col, As + c * 1024);
            GLOAD16(ab + (size_t)(n0  + row) * HW_ + mc + col, Bs + c * 1024);
        }
        __syncthreads();
        #pragma unroll
        for (int ks = 0; ks < 2; ks++) {
            bf16x8 af[4], bg[4];
            #pragma unroll
            for (int mi = 0; mi < 4; mi++) {
                int row  = wr * 64 + mi * 16 + (lane & 15);
                int slot = (ks * 4 + (lane >> 4)) ^ (row & 7);
                af[mi] = *(const bf16x8*)(As + row * 128 + slot * 16);
                int rb  = wc * 64 + mi * 16 + (lane & 15);
                int sb  = (ks * 4 + (lane >> 4)) ^ (rb & 7);
                bg[mi] = *(const bf16x8*)(Bs + rb * 128 + sb * 16);
            }
            #pragma unroll
            for (int mi = 0; mi < 4; mi++)
                #pragma unroll
                for (int ni = 0; ni < 4; ni++)
                    acc[mi][ni] = __builtin_amdgcn_mfma_f32_16x16x32_bf16(
                        af[mi], bg[ni], acc[mi][ni], 0, 0, 0);
        }
        __syncthreads();
    }

    const float gp = gamma_pam[0];
    float* ob = out + (size_t)b * CT_ * HW_;
    #pragma unroll
    for (int mi = 0; mi < 4; mi++)
        #pragma unroll
        for (int ni = 0; ni < 4; ni++)
            #pragma unroll
            for (int r = 0; r < 4; r++)
                ob[(size_t)(ct0 + wr * 64 + mi * 16 + (lane >> 4) * 4 + r) * HW_
                   + n0 + wc * 64 + ni * 16 + (lane & 15)] = gp * acc[mi][ni][r];
}

// ---------------------------------------------------------------------------
// Split: xhi = bf16(x), xlo = bf16(x - xhi).  [b][c][p] layout.
// ---------------------------------------------------------------------------
__global__ __launch_bounds__(256)
void k_split(const float* __restrict__ x, u16* __restrict__ xhi,
             u16* __restrict__ xlo)
{
    for (int i = blockIdx.x * 256 + threadIdx.x; i < 2097152; i += 2048 * 256) {
        float4 v = ((const float4*)x)[i];
        ushort4 h, l;
        h.x = f2bf(v.x); h.y = f2bf(v.y); h.z = f2bf(v.z); h.w = f2bf(v.w);
        l.x = f2bf(v.x - bf2f(h.x)); l.y = f2bf(v.y - bf2f(h.y));
        l.z = f2bf(v.z - bf2f(h.z)); l.w = f2bf(v.w - bf2f(h.w));
        ((ushort4*)xhi)[i] = h;
        ((ushort4*)xlo)[i] = l;
    }
}

// ---------------------------------------------------------------------------
// CAM gram via split-precision MFMA: part[b][ch][c][d] over 256-n slice.
// gram = hi.hi + hi.lo + lo.hi (fp32-equivalent accuracy).
// ---------------------------------------------------------------------------
__global__ __launch_bounds__(256)
void k_cam_gram(const u16* __restrict__ xhi, const u16* __restrict__ xlo,
                float* __restrict__ part)
{
    __shared__ char Sh[32768];                 // 128 rows x 256B (hi)
    __shared__ char Sl[32768];                 // (lo)
    const int b = blockIdx.y, ch = blockIdx.x; // ch: 0..31, covers 256 n
    const int tid = threadIdx.x, lane = tid & 63, w = tid >> 6;
    const u16* hb = xhi + (size_t)b * C_ * P_;
    const u16* lb = xlo + (size_t)b * C_ * P_;

    f32x4 acc[8][2];
    #pragma unroll
    for (int mi = 0; mi < 8; mi++) {
        acc[mi][0] = (f32x4){0.f, 0.f, 0.f, 0.f};
        acc[mi][1] = (f32x4){0.f, 0.f, 0.f, 0.f};
    }

    for (int kc = 0; kc < 2; kc++) {
        int n0 = ch * 256 + kc * 128;
        #pragma unroll
        for (int i = 0; i < 8; i++) {
            int c4  = w * 8 + i;               // 0..31, 4 rows each
            int row = c4 * 4 + (lane >> 4);
            int col = ((lane & 15) ^ (row & 7)) * 8;
            GLOAD16(hb + (size_t)row * P_ + n0 + col, Sh + c4 * 1024);
            GLOAD16(lb + (size_t)row * P_ + n0 + col, Sl + c4 * 1024);
        }
        __syncthreads();
        #pragma unroll
        for (int ks = 0; ks < 4; ks++) {
            bf16x8 bh[2], bl[2];
            #pragma unroll
            for (int ni = 0; ni < 2; ni++) {
                int rb = w * 32 + ni * 16 + (lane & 15);
                int sb = (ks * 4 + (lane >> 4)) ^ (rb & 7);
                bh[ni] = *(const bf16x8*)(Sh + rb * 256 + sb * 16);
                bl[ni] = *(const bf16x8*)(Sl + rb * 256 + sb * 16);
            }
            #pragma unroll
            for (int mi = 0; mi < 8; mi++) {
                int ra = mi * 16 + (lane & 15);
                int sa = (ks * 4 + (lane >> 4)) ^ (ra & 7);
                bf16x8 ah = *(const bf16x8*)(Sh + ra * 256 + sa * 16);
                bf16x8 al = *(const bf16x8*)(Sl + ra * 256 + sa * 16);
                #pragma unroll
                for (int ni = 0; ni < 2; ni++) {
                    acc[mi][ni] = __builtin_amdgcn_mfma_f32_16x16x32_bf16(
                        ah, bh[ni], acc[mi][ni], 0, 0, 0);
                    acc[mi][ni] = __builtin_amdgcn_mfma_f32_16x16x32_bf16(
                        ah, bl[ni], acc[mi][ni], 0, 0, 0);
                    acc[mi][ni] = __builtin_amdgcn_mfma_f32_16x16x32_bf16(
                        al, bh[ni], acc[mi][ni], 0, 0, 0);
                }
            }
        }
        __syncthreads();
    }

    float* pb = part + ((size_t)(b * 32 + ch)) * 16384;
    #pragma unroll
    for (int mi = 0; mi < 8; mi++)
        #pragma unroll
        for (int ni = 0; ni < 2; ni++)
            #pragma unroll
            for (int r = 0; r < 4; r++) {
                int c = mi * 16 + (lane >> 4) * 4 + r;
                int d = w * 32 + ni * 16 + (lane & 15);
                pb[c * 128 + d] = acc[mi][ni][r];
            }
}

// ---------------------------------------------------------------------------
// CAM reduce + negated softmax -> bf16, pre-scaled by gamma_cam.
// ---------------------------------------------------------------------------
__global__ __launch_bounds__(128)
void k_cam_reduce(const float* __restrict__ part,
                  const float* __restrict__ gamma_cam, u16* __restrict__ acam16)
{
    const int b = blockIdx.y, c = blockIdx.x;
    const int d = threadIdx.x;
    float s = 0.f;
    for (int ch = 0; ch < 32; ch++)
        s += part[(((size_t)(b * 32 + ch)) * C_ + c) * C_ + d];
    float mn = s;
    #pragma unroll
    for (int off = 32; off; off >>= 1) mn = fminf(mn, __shfl_xor(mn, off));
    __shared__ float m1[2], m2[2];
    if ((d & 63) == 0) m1[d >> 6] = mn;
    __syncthreads();
    mn = fminf(m1[0], m1[1]);
    float p = __expf(mn - s);
    float sum = p;
    #pragma unroll
    for (int off = 32; off; off >>= 1) sum += __shfl_xor(sum, off);
    if ((d & 63) == 0) m2[d >> 6] = sum;
    __syncthreads();
    sum = m2[0] + m2[1];
    acam16[((size_t)(b * C_ + c)) * C_ + d] = f2bf(gamma_cam[0] * p / sum);
}

__global__ __launch_bounds__(256)
void k_tim_gram(const float* __restrict__ x, float* __restrict__ e_t)
{
    const int b = blockIdx.y, c = blockIdx.x;
    const int tid = threadIdx.x;
    const float* xb = x + ((size_t)(b * C_ + c)) * P_;
    float acc[8][8] = {};
    for (int r = 0; r < 4; r++) {
        int hw = r * 256 + tid;
        float xv[8];
        #pragma unroll
        for (int t = 0; t < 8; t++) xv[t] = xb[t * HW_ + hw];
        #pragma unroll
        for (int t = 0; t < 8; t++)
            #pragma unroll
            for (int s2 = 0; s2 < 8; s2++)
                acc[t][s2] += xv[t] * xv[s2];
    }
    __shared__ float sm[4][64];
    const int lane = tid & 63, wid = tid >> 6;
    #pragma unroll
    for (int u = 0; u < 64; u++) {
        float vv = acc[u >> 3][u & 7];
        #pragma unroll
        for (int off = 32; off; off >>= 1) vv += __shfl_xor(vv, off);
        if (lane == 0) sm[wid][u] = vv;
    }
    __syncthreads();
    if (tid < 64) {
        float vv = sm[0][tid] + sm[1][tid] + sm[2][tid] + sm[3][tid];
        atomicAdd(&e_t[b * 64 + tid], vv);
    }
}

__global__ __launch_bounds__(512)
void k_tim_softmax(const float* __restrict__ e_t, float* __restrict__ a_t)
{
    const int tid = threadIdx.x;
    float v = e_t[tid];
    float mn = v;
    #pragma unroll
    for (int off = 4; off; off >>= 1) mn = fminf(mn, __shfl_xor(mn, off, 8));
    float p = __expf(mn - v);
    float s = p;
    #pragma unroll
    for (int off = 4; off; off >>= 1) s += __shfl_xor(s, off, 8);
    a_t[tid] = p / s;
}

// ---------------------------------------------------------------------------
// X' = 3x + gt * (TIM t-mix of x) -> bf16. Block: one (b,c) row.
// ---------------------------------------------------------------------------
__global__ __launch_bounds__(256)
void k_xprime(const float* __restrict__ x, const float* __restrict__ atim,
              const float* __restrict__ gamma_tim, u16* __restrict__ Xp)
{
    const int b = blockIdx.y, c = blockIdx.x;
    const size_t base = ((size_t)(b * C_ + c)) * P_;
    const int tid = threadIdx.x;
    const float gt = gamma_tim[0];

    float4 xv[8];
    #pragma unroll
    for (int t = 0; t < 8; t++)
        xv[t] = *(const float4*)&x[base + t * HW_ + tid * 4];

    #pragma unroll
    for (int t = 0; t < 8; t++) {
        float4 o = make_float4(3.f * xv[t].x, 3.f * xv[t].y,
                               3.f * xv[t].z, 3.f * xv[t].w);
        #pragma unroll
        for (int s = 0; s < 8; s++) {
            float w = gt * atim[b * 64 + t * 8 + s];
            o.x += w * xv[s].x; o.y += w * xv[s].y;
            o.z += w * xv[s].z; o.w += w * xv[s].w;
        }
        ushort4 pk;
        pk.x = f2bf(o.x); pk.y = f2bf(o.y); pk.z = f2bf(o.z); pk.w = f2bf(o.w);
        *(ushort4*)&Xp[base + t * HW_ + tid * 4] = pk;
    }
}

// ---------------------------------------------------------------------------
// CAM AV MFMA + fused epilogue: out += acam16 @ x  + X'.
// ---------------------------------------------------------------------------
__global__ __launch_bounds__(256)
void k_cam_av(const u16* __restrict__ acam16, const u16* __restrict__ xT,
              const u16* __restrict__ Xp, float* __restrict__ out)
{
    const int b  = blockIdx.y;
    const int p0 = blockIdx.x * 128;
    const int tid = threadIdx.x, lane = tid & 63, w = tid >> 6;

    const u16* Ab = acam16 + (size_t)b * C_ * C_;
    const u16* Bb = xT + ((size_t)(b * P_ + p0 + w * 32)) * C_;

    f32x4 acc[8][2];
    #pragma unroll
    for (int mi = 0; mi < 8; mi++) {
        acc[mi][0] = (f32x4){0.f, 0.f, 0.f, 0.f};
        acc[mi][1] = (f32x4){0.f, 0.f, 0.f, 0.f};
    }

    bf16x8 bg[4][2];
    #pragma unroll
    for (int ks = 0; ks < 4; ks++)
        #pragma unroll
        for (int ni = 0; ni < 2; ni++)
            bg[ks][ni] = *(const bf16x8*)(Bb +
                (size_t)(ni * 16 + (lane & 15)) * C_ + ks * 32 + (lane >> 4) * 8);

    #pragma unroll
    for (int mi = 0; mi < 8; mi++) {
        #pragma unroll
        for (int ks = 0; ks < 4; ks++) {
            bf16x8 af = *(const bf16x8*)(Ab +
                (size_t)(mi * 16 + (lane & 15)) * C_ + ks * 32 + (lane >> 4) * 8);
            acc[mi][0] = __builtin_amdgcn_mfma_f32_16x16x32_bf16(
                af, bg[ks][0], acc[mi][0], 0, 0, 0);
            acc[mi][1] = __builtin_amdgcn_mfma_f32_16x16x32_bf16(
                af, bg[ks][1], acc[mi][1], 0, 0, 0);
        }
    }

    float* ob = out + (size_t)b * C_ * P_;
    const u16* xp = Xp + (size_t)b * C_ * P_;
    #pragma unroll
    for (int mi = 0; mi < 8; mi++)
        #pragma unroll
        for (int ni = 0; ni < 2; ni++)
            #pragma unroll
            for (int r = 0; r < 4; r++) {
                int c = mi * 16 + (lane >> 4) * 4 + r;
                int p = p0 + w * 32 + ni * 16 + (lane & 15);
                size_t i = (size_t)c * P_ + p;
                ob[i] += acc[mi][ni][r] + bf2f(xp[i]);
            }
}

// ---------------------------------------------------------------------------
extern "C" void kernel_launch(void* const* d_in, const int* in_sizes, int n_in,
                              void* d_out, int out_size, void* d_ws, size_t ws_size,
                              hipStream_t stream)
{
    (void)in_sizes; (void)n_in; (void)out_size; (void)ws_size;
    const float* x  = (const float*)d_in[0];
    const float* Wq = (const float*)d_in[1];
    const float* bq = (const float*)d_in[2];
    const float* Wk = (const float*)d_in[3];
    const float* bk = (const float*)d_in[4];
    const float* Wv = (const float*)d_in[5];
    const float* bv = (const float*)d_in[6];
    const float* gp = (const float*)d_in[7];
    const float* gc = (const float*)d_in[8];
    const float* gt = (const float*)d_in[9];
    float* out = (float*)d_out;
    char*  ws  = (char*)d_ws;

    const size_t MiB = 1u << 20;
    u16*   xT     = (u16*)(ws + 0);              // 16 MiB [prep -> cam_av]
    u16*   qtb    = (u16*)(ws + 16 * MiB);       // 2 MiB  [qkv -> energy]
    u16*   ktb    = (u16*)(ws + 18 * MiB);       // 2 MiB
    u16*   v16    = (u16*)(ws + 20 * MiB);       // 16 MiB [qkv -> pv]
    u16*   Xp16   = (u16*)(ws + 20 * MiB);       //   alias, [xprime -> cam_av]
    float* Ebuf   = (float*)(ws + 36 * MiB);     // 32 MiB [energy -> softmax]
    u16*   xhi    = (u16*)(ws + 36 * MiB);       //   alias, [split -> cam_gram]
    u16*   xlo    = (u16*)(ws + 52 * MiB);       //   alias
    u16*   A16    = (u16*)(ws + 68 * MiB);       // 16 MiB [softmax -> pv]
    float* part   = (float*)(ws + 68 * MiB);     //   alias, [gram -> reduce]
    u16*   acam16 = (u16*)(ws + 84 * MiB);       // 32 KB
    u16*   Wall   = (u16*)(ws + 84 * MiB + 65536);
    float* ball   = (float*)(ws + 84 * MiB + 131072);
    float* etim   = (float*)(ws + 84 * MiB + 139264);
    float* atim   = (float*)(ws + 84 * MiB + 143360);

    hipMemsetAsync(etim, 0, 512 * sizeof(float), stream);

    k_wcast      <<<dim3(80),      256, 0, stream>>>(Wq, bq, Wk, bk, Wv, bv,
                                                     Wall, ball);
    k_prep       <<<dim3(64, 8),   256, 0, stream>>>(x, xT);
    k_qkv        <<<dim3(64, 8),   256, 0, stream>>>(xT, Wall, ball,
                                                     qtb, ktb, v16);
    k_energy     <<<dim3(8, 8, 8), 256, 0, stream>>>(qtb, ktb, Ebuf);
    k_softmax    <<<dim3(8192),    256, 0, stream>>>(Ebuf, A16);
    k_split      <<<dim3(2048),    256, 0, stream>>>(x, xhi, xlo);
    k_tim_gram   <<<dim3(128, 8),  256, 0, stream>>>(x, etim);
    k_tim_softmax<<<dim3(1),       512, 0, stream>>>(etim, atim);
    k_pv         <<<dim3(8, 8, 8), 256, 0, stream>>>(v16, A16, gp, out);
    // v16 and A16 dead -> Xp16 / part become live
    k_xprime     <<<dim3(128, 8),  256, 0, stream>>>(x, atim, gt, Xp16);
    k_cam_gram   <<<dim3(32, 8),   256, 0, stream>>>(xhi, xlo, part);
    k_cam_reduce <<<dim3(128, 8),  128, 0, stream>>>(part, gc, acam16);
    k_cam_av     <<<dim3(64, 8),   256, 0, stream>>>(acam16, xT, Xp16, out);
}